// Round 13
// baseline (416.238 us; speedup 1.0000x reference)
//
#include <hip/hip_runtime.h>
#include <cstdint>
#include <cstddef>

#define B_  16
#define N_  576
#define D_  768
#define H_  12
#define HD_ 64
#define M_  128
#define J_  704   // N_ + M_

typedef unsigned short u16;
typedef __attribute__((ext_vector_type(8))) short bf16x8;
typedef __attribute__((ext_vector_type(4))) float f32x4;
typedef __attribute__((ext_vector_type(4))) unsigned short u16x4;
typedef __attribute__((ext_vector_type(8))) unsigned short u16x8;

// ---------------- helpers ----------------

__device__ __forceinline__ float softplus_f(float x) {
    return (x > 20.f) ? x : log1pf(expf(x));
}

__device__ __forceinline__ float wred_sum64(float v) {
#pragma unroll
    for (int m = 1; m < 64; m <<= 1) v += __shfl_xor(v, m, 64);
    return v;
}

__device__ __forceinline__ u16 bf16_rne(float f) {
    unsigned int u = __float_as_uint(f);
    unsigned int r = u + 0x7FFFu + ((u >> 16) & 1u);
    return (u16)(r >> 16);
}
__device__ __forceinline__ float bf16_tof(u16 h) {
    return __uint_as_float(((unsigned int)h) << 16);
}

// expmap0 total multiplier (division- and tanhf-free: v_rcp/v_exp).
__device__ __forceinline__ float expmap0_factor(float n2, float sc, float* n2out) {
    const float ATANH_1M1E5 = 6.1030335f;     // artanh(1 - 1e-5)
    const float LOG2E2 = 2.8853900817779268f; // 2*log2(e)
    float rsc = __builtin_amdgcn_rcpf(sc);
    float n0 = __builtin_amdgcn_sqrtf(fmaxf(n2, 1e-15f));
    float f1 = fminf(1.f, (ATANH_1M1E5 * rsc) * __builtin_amdgcn_rcpf(n0));  // pre-clip
    float n1 = n0 * f1;
    float a  = sc * n1;
    float e2a = __builtin_amdgcn_exp2f(a * LOG2E2);
    float th  = 1.f - 2.f * __builtin_amdgcn_rcpf(e2a + 1.f);   // tanh(a), a not tiny
    float yfac  = th * __builtin_amdgcn_rcpf(a);
    float f2 = fminf(1.f, 0.99999f * __builtin_amdgcn_rcpf(th)); // post-clip
    float fn = (th * rsc) * f2;
    *n2out = fn * fn;
    return f1 * yfac * f2;
}

__device__ __forceinline__ float artanh_fast(float z) {  // z in [0, 1-1e-7]
    return 0.5f * __logf((1.f + z) / (1.f - z));
}

// global -> LDS direct copy, 16B per lane (wave-uniform LDS base + lane*16)
typedef const __attribute__((address_space(1))) unsigned int* gas_u32;
typedef __attribute__((address_space(3))) unsigned int* las_u32;
__device__ __forceinline__ void gload_lds16(const u16* g, u16* l) {
    __builtin_amdgcn_global_load_lds((gas_u32)(const void*)g, (las_u32)(void*)l, 16, 0, 0);
}

// ---------------- kernel 0a: f32 -> bf16 hi/lo split (x) ----------------
__global__ __launch_bounds__(256) void split_bf16_kernel(
    const float* __restrict__ src, u16* __restrict__ hi, u16* __restrict__ lo, int n4)
{
    int i = blockIdx.x * 256 + threadIdx.x;
    if (i >= n4) return;
    float4 v = ((const float4*)src)[i];
    u16x4 h, l;
    h[0] = bf16_rne(v.x); l[0] = bf16_rne(v.x - bf16_tof(h[0]));
    h[1] = bf16_rne(v.y); l[1] = bf16_rne(v.y - bf16_tof(h[1]));
    h[2] = bf16_rne(v.z); l[2] = bf16_rne(v.z - bf16_tof(h[2]));
    h[3] = bf16_rne(v.w); l[3] = bf16_rne(v.w - bf16_tof(h[3]));
    ((u16x4*)hi)[i] = h;
    ((u16x4*)lo)[i] = l;
}

// ---------------- kernel 0b: split all 4 weight matrices in one launch ----------------
__global__ __launch_bounds__(256) void split_w4_kernel(
    const float* __restrict__ W0, const float* __restrict__ W1,
    const float* __restrict__ W2, const float* __restrict__ W3,
    u16* __restrict__ H0, u16* __restrict__ L0, u16* __restrict__ H1, u16* __restrict__ L1,
    u16* __restrict__ H2, u16* __restrict__ L2, u16* __restrict__ H3, u16* __restrict__ L3)
{
    int i = blockIdx.x * 256 + threadIdx.x;   // < WSZ/4 = 147456
    const int wsel = blockIdx.y;
    const float* src = wsel == 0 ? W0 : (wsel == 1 ? W1 : (wsel == 2 ? W2 : W3));
    u16* hi = wsel == 0 ? H0 : (wsel == 1 ? H1 : (wsel == 2 ? H2 : H3));
    u16* lo = wsel == 0 ? L0 : (wsel == 1 ? L1 : (wsel == 2 ? L2 : L3));
    float4 v = ((const float4*)src)[i];
    u16x4 h, l;
    h[0] = bf16_rne(v.x); l[0] = bf16_rne(v.x - bf16_tof(h[0]));
    h[1] = bf16_rne(v.y); l[1] = bf16_rne(v.y - bf16_tof(h[1]));
    h[2] = bf16_rne(v.z); l[2] = bf16_rne(v.z - bf16_tof(h[2]));
    h[3] = bf16_rne(v.w); l[3] = bf16_rne(v.w - bf16_tof(h[3]));
    ((u16x4*)hi)[i] = h;
    ((u16x4*)lo)[i] = l;
}

// ---------------- kernel 1: QKV projection + FUSED hyperbolic maps ----------------
// 128x256 tile (4 waves, each 64 rows x 128 cols = 2 heads): 96 MFMA per K-step
// per wave between barriers, halving barrier events and staging per MFMA.
__global__ __launch_bounds__(256) void gemm_qkv_mfma(
    const u16* __restrict__ xh, const u16* __restrict__ xl,
    const u16* __restrict__ Wh0, const u16* __restrict__ Wl0,
    const u16* __restrict__ Wh1, const u16* __restrict__ Wl1,
    const u16* __restrict__ Wh2, const u16* __restrict__ Wl2,
    const float* __restrict__ bq, const float* __restrict__ bk, const float* __restrict__ bv,
    u16* __restrict__ Qb0, u16* __restrict__ Qb1, u16* __restrict__ Qb2,
    u16* __restrict__ Kb0, u16* __restrict__ Kb1, u16* __restrict__ Kb2,
    u16* __restrict__ gV0, u16* __restrict__ gV1,
    float* __restrict__ x2q, float* __restrict__ y2g, float* __restrict__ gm1,
    float* __restrict__ rbj,
    const float* __restrict__ curv_raw)
{
    __shared__ u16 Ah[4096], Al[4096];     // 128 rows x 32 k
    __shared__ u16 Bh[8192], Bl[8192];     // 256 cols x 32 k
    const int tid = threadIdx.x;
    const int w = tid >> 6, lane = tid & 63;
    const int wr = w >> 1, wc = w & 1;
    const int lrow = lane & 15, lk8 = (lane >> 4) << 3;
    const int lg = lane >> 4;
    // XCD-band swizzle: 648 blocks = 8 XCDs x (9 mt x 9 yb)
    const int bid = blockIdx.x;
    const int xcd = bid & 7, ser = bid >> 3;       // ser < 81
    const int mt = xcd * 9 + (ser % 9);
    const int yb = ser / 9;                        // < 9
    const int which = yb / 3, ct = yb % 3;
    const u16* Bp_h = which == 0 ? Wh0 : (which == 1 ? Wh1 : Wh2);
    const u16* Bp_l = which == 0 ? Wl0 : (which == 1 ? Wl1 : Wl2);
    const int row0 = mt * 128, col0 = ct * 256;

    // per-wave staging addresses: A frags {2w,2w+1}, B frags {4w..4w+3}
    const size_t aA0 = (size_t)(row0 + (2 * w + 0) * 16 + lrow) * 768 + lk8;
    const size_t aA1 = aA0 + 16 * 768;
    const size_t bB0 = (size_t)(col0 + (4 * w + 0) * 16 + lrow) * 768 + lk8;
    const size_t bB1 = bB0 + 16 * 768;
    const size_t bB2 = bB0 + 32 * 768;
    const size_t bB3 = bB0 + 48 * 768;
    u16* lAh0 = Ah + (2 * w) * 512;     u16* lAh1 = lAh0 + 512;
    u16* lAl0 = Al + (2 * w) * 512;     u16* lAl1 = lAl0 + 512;
    u16* lBh0 = Bh + (4 * w) * 512;     u16* lBh1 = lBh0 + 512;
    u16* lBh2 = lBh0 + 1024;            u16* lBh3 = lBh0 + 1536;
    u16* lBl0 = Bl + (4 * w) * 512;     u16* lBl1 = lBl0 + 512;
    u16* lBl2 = lBl0 + 1024;            u16* lBl3 = lBl0 + 1536;

    auto STAGE = [&](int k0) {
        gload_lds16(xh + aA0 + k0, lAh0);
        gload_lds16(xh + aA1 + k0, lAh1);
        gload_lds16(xl + aA0 + k0, lAl0);
        gload_lds16(xl + aA1 + k0, lAl1);
        gload_lds16(Bp_h + bB0 + k0, lBh0);
        gload_lds16(Bp_h + bB1 + k0, lBh1);
        gload_lds16(Bp_h + bB2 + k0, lBh2);
        gload_lds16(Bp_h + bB3 + k0, lBh3);
        gload_lds16(Bp_l + bB0 + k0, lBl0);
        gload_lds16(Bp_l + bB1 + k0, lBl1);
        gload_lds16(Bp_l + bB2 + k0, lBl2);
        gload_lds16(Bp_l + bB3 + k0, lBl3);
    };

    f32x4 acc[4][8];
#pragma unroll
    for (int i = 0; i < 4; ++i)
#pragma unroll
        for (int j = 0; j < 8; ++j) acc[i][j] = (f32x4){0.f, 0.f, 0.f, 0.f};

    STAGE(0);
    __syncthreads();

    const int lo8 = lane * 8;
    for (int k0 = 0; k0 < 768; k0 += 32) {
        bf16x8 aH[4], aL[4], bH[8], bL[8];
#pragma unroll
        for (int i = 0; i < 4; ++i) {
            aH[i] = *(const bf16x8*)(Ah + (wr * 4 + i) * 512 + lo8);
            aL[i] = *(const bf16x8*)(Al + (wr * 4 + i) * 512 + lo8);
        }
#pragma unroll
        for (int j = 0; j < 8; ++j) {
            bH[j] = *(const bf16x8*)(Bh + (wc * 8 + j) * 512 + lo8);
            bL[j] = *(const bf16x8*)(Bl + (wc * 8 + j) * 512 + lo8);
        }
        __syncthreads();                 // all waves done reading LDS
        if (k0 < 736) STAGE(k0 + 32);    // overwrite same buffer; hides under MFMA
#pragma unroll
        for (int mi = 0; mi < 4; ++mi)
#pragma unroll
            for (int ni = 0; ni < 8; ++ni) {
                acc[mi][ni] = __builtin_amdgcn_mfma_f32_16x16x32_bf16(aH[mi], bH[ni], acc[mi][ni], 0, 0, 0);
                acc[mi][ni] = __builtin_amdgcn_mfma_f32_16x16x32_bf16(aH[mi], bL[ni], acc[mi][ni], 0, 0, 0);
                acc[mi][ni] = __builtin_amdgcn_mfma_f32_16x16x32_bf16(aL[mi], bH[ni], acc[mi][ni], 0, 0, 0);
            }
        __syncthreads();                 // staging drained before next reads
    }

    // ---------------- fused epilogue (2 heads per wave) ----------------
    const float* bias = which == 0 ? bq : (which == 1 ? bk : bv);
    const int hA = ct * 4 + wc * 2;                // heads hA, hA+1
    const int rbase = row0 + wr * 64 + (lg << 2);
    const float c  = softplus_f(curv_raw[0]);
    const float sc = sqrtf(c);
    float bvv[8];
#pragma unroll
    for (int ni = 0; ni < 8; ++ni)
        bvv[ni] = bias[(hA + (ni >> 2)) * 64 + (ni & 3) * 16 + lrow];

#pragma unroll
    for (int mi = 0; mi < 4; ++mi) {
        float v4[8][4];   // [ni][r]
#pragma unroll
        for (int ni = 0; ni < 8; ++ni) {
            f32x4 a = acc[mi][ni];
#pragma unroll
            for (int r = 0; r < 4; ++r) v4[ni][r] = a[r] + bvv[ni];
        }
        // per-row sumsq per head: in-lane ni-sum (4 terms) then 4-step lrow butterfly
        float f_[2][4], n2o_[2][4];
#pragma unroll
        for (int hs = 0; hs < 2; ++hs)
#pragma unroll
            for (int r = 0; r < 4; ++r) {
                float s = v4[hs * 4 + 0][r] * v4[hs * 4 + 0][r];
#pragma unroll
                for (int ni = 1; ni < 4; ++ni)
                    s = fmaf(v4[hs * 4 + ni][r], v4[hs * 4 + ni][r], s);
#pragma unroll
                for (int m = 1; m < 16; m <<= 1) s += __shfl_xor(s, m, 64);
                f_[hs][r] = expmap0_factor(s, sc, &n2o_[hs][r]);
            }
        const int row0g = rbase + mi * 16;          // 4 consecutive rows, same batch
        const int bb = row0g / 576;
        const int nn0 = row0g - bb * 576;
#pragma unroll
        for (int hs = 0; hs < 2; ++hs) {
            const int h = hA + hs;
            const size_t gbase = ((size_t)(bb * 12 + h)) * 576 + nn0;
            if (which == 2) {
                float gmm[4];
#pragma unroll
                for (int r = 0; r < 4; ++r)
                    gmm[r] = 2.f * __builtin_amdgcn_rcpf(fmaxf(1.f - c * n2o_[hs][r], 1e-15f));
                if (lrow == 0) {
#pragma unroll
                    for (int r = 0; r < 4; ++r) gm1[gbase + r] = gmm[r] - 1.f;
                }
#pragma unroll
                for (int ni = 0; ni < 4; ++ni) {
                    const int hd = ni * 16 + lrow;
                    u16x4 hsv, lsv;
#pragma unroll
                    for (int r = 0; r < 4; ++r) {
                        float gv = v4[hs * 4 + ni][r] * f_[hs][r] * gmm[r];
                        u16 hb = bf16_rne(gv);
                        hsv[r] = hb;
                        lsv[r] = bf16_rne(gv - bf16_tof(hb));
                    }
                    const size_t dst = (((size_t)(bb * 12 + h)) * 64 + hd) * 576 + nn0;
                    *(u16x4*)(gV0 + dst) = hsv;
                    *(u16x4*)(gV1 + dst) = lsv;
                }
            } else {
                float* scal = which == 0 ? x2q : y2g;
                if (lrow == 0) {
#pragma unroll
                    for (int r = 0; r < 4; ++r) scal[gbase + r] = n2o_[hs][r];
                    if (which == 1) {
#pragma unroll
                        for (int r = 0; r < 4; ++r)
                            rbj[gbase + r] = __builtin_amdgcn_rcpf(fmaf(-c, n2o_[hs][r], 1.f));
                    }
                }
                u16* P0 = which == 0 ? Qb0 : Kb0;
                u16* P1 = which == 0 ? Qb1 : Kb1;
                u16* P2 = which == 0 ? Qb2 : Kb2;
#pragma unroll
                for (int ni = 0; ni < 4; ++ni) {
                    const int hd = ni * 16 + lrow;
#pragma unroll
                    for (int r = 0; r < 4; ++r) {
                        float y = v4[hs * 4 + ni][r] * f_[hs][r];
                        u16 hb = bf16_rne(y);
                        float r1 = y - bf16_tof(hb);
                        u16 mb = bf16_rne(r1);
                        u16 lb2 = bf16_rne(r1 - bf16_tof(mb));
                        const size_t off = (gbase + r) * 64 + hd;
                        P0[off] = hb; P1[off] = mb; P2[off] = lb2;
                    }
                }
            }
        }
    }
}

// ---------------- kernel 5: output projection (split-bf16 MFMA, pipelined) ----------------
__global__ __launch_bounds__(256) void gemm_o_mfma(
    const u16* __restrict__ Oh, const u16* __restrict__ Ol,
    const u16* __restrict__ Wh, const u16* __restrict__ Wl,
    const float* __restrict__ bo, float* __restrict__ out)
{
    __shared__ u16 Ah[4096], Al[4096], Bh[4096], Bl[4096];
    const int tid = threadIdx.x;
    const int w = tid >> 6, lane = tid & 63;
    const int wr = w >> 1, wc = w & 1;
    const int lrow = lane & 15, lk8 = (lane >> 4) << 3;
    // 432 blocks = 8 XCDs x (9 mt x 6 ct)
    const int bid = blockIdx.x;
    const int xcd = bid & 7, ser = bid >> 3;       // ser < 54
    const int mt = xcd * 9 + (ser % 9);
    const int ct = ser / 9;                        // < 6
    const int row0 = mt * 128, col0 = ct * 128;

    const size_t a0 = (size_t)(row0 + (2 * w + 0) * 16 + lrow) * 768 + lk8;
    const size_t a1 = a0 + 16 * 768;
    const size_t b0 = (size_t)(col0 + (2 * w + 0) * 16 + lrow) * 768 + lk8;
    const size_t b1 = b0 + 16 * 768;
    u16* lAh0 = Ah + (2 * w) * 512; u16* lAh1 = lAh0 + 512;
    u16* lAl0 = Al + (2 * w) * 512; u16* lAl1 = lAl0 + 512;
    u16* lBh0 = Bh + (2 * w) * 512; u16* lBh1 = lBh0 + 512;
    u16* lBl0 = Bl + (2 * w) * 512; u16* lBl1 = lBl0 + 512;

    auto STAGE = [&](int k0) {
        gload_lds16(Oh + a0 + k0, lAh0);
        gload_lds16(Oh + a1 + k0, lAh1);
        gload_lds16(Ol + a0 + k0, lAl0);
        gload_lds16(Ol + a1 + k0, lAl1);
        gload_lds16(Wh + b0 + k0, lBh0);
        gload_lds16(Wh + b1 + k0, lBh1);
        gload_lds16(Wl + b0 + k0, lBl0);
        gload_lds16(Wl + b1 + k0, lBl1);
    };

    f32x4 acc[4][4];
#pragma unroll
    for (int i = 0; i < 4; ++i)
#pragma unroll
        for (int j = 0; j < 4; ++j) acc[i][j] = (f32x4){0.f, 0.f, 0.f, 0.f};

    STAGE(0);
    __syncthreads();

    const int lo8 = lane * 8;
    for (int k0 = 0; k0 < 768; k0 += 32) {
        bf16x8 aH[4], aL[4], bH[4], bL[4];
#pragma unroll
        for (int i = 0; i < 4; ++i) {
            aH[i] = *(const bf16x8*)(Ah + (wr * 4 + i) * 512 + lo8);
            aL[i] = *(const bf16x8*)(Al + (wr * 4 + i) * 512 + lo8);
            bH[i] = *(const bf16x8*)(Bh + (wc * 4 + i) * 512 + lo8);
            bL[i] = *(const bf16x8*)(Bl + (wc * 4 + i) * 512 + lo8);
        }
        __syncthreads();
        if (k0 < 736) STAGE(k0 + 32);
#pragma unroll
        for (int mi = 0; mi < 4; ++mi)
#pragma unroll
            for (int ni = 0; ni < 4; ++ni) {
                acc[mi][ni] = __builtin_amdgcn_mfma_f32_16x16x32_bf16(aH[mi], bH[ni], acc[mi][ni], 0, 0, 0);
                acc[mi][ni] = __builtin_amdgcn_mfma_f32_16x16x32_bf16(aH[mi], bL[ni], acc[mi][ni], 0, 0, 0);
                acc[mi][ni] = __builtin_amdgcn_mfma_f32_16x16x32_bf16(aL[mi], bH[ni], acc[mi][ni], 0, 0, 0);
            }
        __syncthreads();
    }

    const int rbase = row0 + wr * 64 + ((lane >> 4) << 2);
#pragma unroll
    for (int ni = 0; ni < 4; ++ni) {
        const int colg = col0 + wc * 64 + ni * 16 + lrow;
        const float bv_ = bo[colg];
#pragma unroll
        for (int mi = 0; mi < 4; ++mi) {
            f32x4 a = acc[mi][ni];
#pragma unroll
            for (int r = 0; r < 4; ++r) {
                int row = rbase + mi * 16 + r;
                out[(size_t)row * 768 + colg] = a[r] + bv_;
            }
        }
    }
}

// ---------------- kernel 2: per-head centroid maps (once, shared across batch) ----------------
__global__ __launch_bounds__(256) void cent_kernel(
    const float* __restrict__ cent,
    u16* __restrict__ Kc0, u16* __restrict__ Kc1, u16* __restrict__ Kc2,
    u16* __restrict__ gVc0, u16* __restrict__ gVc1,
    float* __restrict__ y2c, float* __restrict__ gm1c, float* __restrict__ rbc,
    const float* __restrict__ curv_raw)
{
    __shared__ float gvt_s[64][65];
    const float c  = softplus_f(curv_raw[0]);
    const float sc = sqrtf(c);
    const int t = blockIdx.x;         // < 24
    const int h = t >> 1, ct = t & 1;
    const int w = threadIdx.x >> 6, lane = threadIdx.x & 63;
#pragma unroll 4
    for (int i = 0; i < 16; ++i) {
        const int m = ct * 64 + w * 16 + i;
        const size_t g = (size_t)h * 128 + m;
        float cv = cent[g * 64 + lane];
        float n2 = wred_sum64(cv * cv);
        float n2o;
        float f = expmap0_factor(n2, sc, &n2o);
        float ky = cv * f;
        u16 kh = bf16_rne(ky);
        float r1 = ky - bf16_tof(kh);
        u16 km = bf16_rne(r1);
        u16 kl = bf16_rne(r1 - bf16_tof(km));
        Kc0[g * 64 + lane] = kh; Kc1[g * 64 + lane] = km; Kc2[g * 64 + lane] = kl;
        float gmm = 2.f * __builtin_amdgcn_rcpf(fmaxf(1.f - c * n2o, 1e-15f));
        gvt_s[lane][w * 16 + i] = ky * gmm;
        if (lane == 0) {
            y2c[g] = n2o; gm1c[g] = gmm - 1.f;
            rbc[g] = __builtin_amdgcn_rcpf(fmaf(-c, n2o, 1.f));
        }
    }
    __syncthreads();
    const int hd = threadIdx.x >> 2, j0 = (threadIdx.x & 3) * 16;
    u16 hb[16], lb[16];
#pragma unroll
    for (int e = 0; e < 16; ++e) {
        float v = gvt_s[hd][j0 + e];
        hb[e] = bf16_rne(v);
        lb[e] = bf16_rne(v - bf16_tof(hb[e]));
    }
    const size_t dst = ((size_t)h * 64 + hd) * 128 + ct * 64 + j0;
    *(u16x8*)(gVc0 + dst)     = *(u16x8*)&hb[0];
    *(u16x8*)(gVc0 + dst + 8) = *(u16x8*)&hb[8];
    *(u16x8*)(gVc1 + dst)     = *(u16x8*)&lb[0];
    *(u16x8*)(gVc1 + dst + 8) = *(u16x8*)&lb[8];
}

// ---------------- kernel 4: fused hyperbolic attention (MFMA, LDS-staged K/V) ----------------
// Logit via the arcosh form of the Poincare distance (exactly 2*artanh(arg)):
// z = 1 + 2c*||x-y||^2 * ra * rb; W = exp2(c2h*lg^2), lg = log2(z + sqrt(z^2-1)).
__global__ __launch_bounds__(256) void attn_kernel(
    const u16* __restrict__ Qb0, const u16* __restrict__ Qb1, const u16* __restrict__ Qb2,
    const u16* __restrict__ Kb0, const u16* __restrict__ Kb1, const u16* __restrict__ Kb2,
    const u16* __restrict__ Kc0, const u16* __restrict__ Kc1, const u16* __restrict__ Kc2,
    const u16* __restrict__ gV0, const u16* __restrict__ gV1,
    const u16* __restrict__ gVc0, const u16* __restrict__ gVc1,
    const float* __restrict__ x2q, const float* __restrict__ y2g, const float* __restrict__ gm1,
    const float* __restrict__ y2c, const float* __restrict__ gm1c,
    const float* __restrict__ rbj, const float* __restrict__ rbc,
    const float* __restrict__ sigma_raw, const float* __restrict__ curv_raw,
    u16* __restrict__ Oh, u16* __restrict__ Ol)
{
    __shared__ __align__(16) u16 Kst[2][3][4096];  // [buf][plane][row*64 + swizzled col]
    __shared__ __align__(16) u16 Vst[2][4096];     // [plane][row*64 + swizzled col]
    __shared__ __align__(16) u16 wb_hi[4][1024];
    __shared__ __align__(16) u16 wb_lo[4][1024];

    const int blk = blockIdx.x;
    const int xcd = blk & 7;
    const int serial = blk >> 3;
    const int bhg = serial / 9;
    const int qt = serial - bhg * 9;
    const int bh = bhg * 8 + xcd;
    const int b = bh / 12, h = bh % 12;
    const float c  = softplus_f(curv_raw[0]);
    const float sc = sqrtf(c);
    const float sig = softplus_f(sigma_raw[h]) + 1e-6f;
    const float coef = -2.f / (c * sig * sig);   // logit = coef * artanh(arg)^2
    const float c2h  = coef * 0.25f * 0.6931471805599453f;  // exp2 basis

    const int tid = threadIdx.x;
    const int w = tid >> 6, lane = tid & 63;
    const int lr = lane & 15, lg = lane >> 4, lo8 = lg * 8;
    const int swl = (lr & 7) << 3;

    const size_t qbase = (size_t)bh * 576 + qt * 64;

    int srow[2], scol[2];
#pragma unroll
    for (int rr = 0; rr < 2; ++rr) {
        int cch = (rr * 4 + w) * 64 + lane;
        srow[rr] = cch >> 3;
        scol[rr] = ((cch & 7) ^ (srow[rr] & 7)) << 3;
    }
    const size_t kb_base = (size_t)bh * 576 * 64;
    const size_t kc_base = (size_t)h * 128 * 64;
    const size_t vb_base = (size_t)bh * 64 * 576;
    const size_t vc_base = (size_t)h * 64 * 128;

    auto stageK = [&](int t, int buf) {
        if (t < 9) {
            const size_t rb = kb_base + (size_t)t * 64 * 64;
#pragma unroll
            for (int rr = 0; rr < 2; ++rr) {
                const size_t so = rb + (size_t)srow[rr] * 64 + scol[rr];
                gload_lds16(Kb0 + so, &Kst[buf][0][(rr * 4 + w) * 512]);
                gload_lds16(Kb1 + so, &Kst[buf][1][(rr * 4 + w) * 512]);
                gload_lds16(Kb2 + so, &Kst[buf][2][(rr * 4 + w) * 512]);
            }
        } else {
            const size_t rb = kc_base + (size_t)(t - 9) * 64 * 64;
#pragma unroll
            for (int rr = 0; rr < 2; ++rr) {
                const size_t so = rb + (size_t)srow[rr] * 64 + scol[rr];
                gload_lds16(Kc0 + so, &Kst[buf][0][(rr * 4 + w) * 512]);
                gload_lds16(Kc1 + so, &Kst[buf][1][(rr * 4 + w) * 512]);
                gload_lds16(Kc2 + so, &Kst[buf][2][(rr * 4 + w) * 512]);
            }
        }
    };
    auto stageV = [&](int t) {
        if (t < 9) {
            const size_t rb = vb_base + (size_t)t * 64;
#pragma unroll
            for (int rr = 0; rr < 2; ++rr) {
                const size_t so = rb + (size_t)srow[rr] * 576 + scol[rr];
                gload_lds16(gV0 + so, &Vst[0][(rr * 4 + w) * 512]);
                gload_lds16(gV1 + so, &Vst[1][(rr * 4 + w) * 512]);
            }
        } else {
            const size_t rb = vc_base + (size_t)(t - 9) * 64;
#pragma unroll
            for (int rr = 0; rr < 2; ++rr) {
                const size_t so = rb + (size_t)srow[rr] * 128 + scol[rr];
                gload_lds16(gVc0 + so, &Vst[0][(rr * 4 + w) * 512]);
                gload_lds16(gVc1 + so, &Vst[1][(rr * 4 + w) * 512]);
            }
        }
    };

    bf16x8 aQh[2], aQm[2], aQl[2];
    {
        const size_t qrow = (qbase + w * 16 + lr) * 64;
#pragma unroll
        for (int kt = 0; kt < 2; ++kt) {
            const size_t o = qrow + kt * 32 + lo8;
            aQh[kt] = *(const bf16x8*)(Qb0 + o);
            aQm[kt] = *(const bf16x8*)(Qb1 + o);
            aQl[kt] = *(const bf16x8*)(Qb2 + o);
        }
    }
    float x2r[4], Pr[4];
#pragma unroll
    for (int r = 0; r < 4; ++r) {
        float x2 = x2q[qbase + w * 16 + lg * 4 + r];
        x2r[r] = x2;
        Pr[r] = (c + c) / fmaf(-c, x2, 1.f);    // 2c * ra, ra = 1/(1-c*x2)
    }

    f32x4 pv[4];
#pragma unroll
    for (int i = 0; i < 4; ++i) pv[i] = (f32x4){0.f, 0.f, 0.f, 0.f};
    float den[4] = {0.f, 0.f, 0.f, 0.f};

    u16* wbh = &wb_hi[w][0];
    u16* wbl = &wb_lo[w][0];

    stageK(0, 0);
    __syncthreads();

    int cur = 0;
    for (int jt = 0; jt < 11; ++jt) {
        const int jb = jt * 64;

        if (jt < 10) stageK(jt + 1, cur ^ 1);
        stageV(jt);

        const float* y2p;
        const float* gm1p;
        const float* rbp;
        if (jt < 9) {
            y2p = y2g + (size_t)bh * 576 + jb;  gm1p = gm1 + (size_t)bh * 576 + jb;
            rbp = rbj + (size_t)bh * 576 + jb;
        } else {
            y2p = y2c + (size_t)h * 128 + (jb - 576); gm1p = gm1c + (size_t)h * 128 + (jb - 576);
            rbp = rbc + (size_t)h * 128 + (jb - 576);
        }

        const u16* kp0 = &Kst[cur][0][0];
        const u16* kp1 = &Kst[cur][1][0];
        const u16* kp2 = &Kst[cur][2][0];
        f32x4 sf[4];
        float y2v[4], gm1v[4], rbv[4];
#pragma unroll
        for (int jf = 0; jf < 4; ++jf) {
            y2v[jf] = y2p[jf * 16 + lr];
            gm1v[jf] = gm1p[jf * 16 + lr];
            rbv[jf] = rbp[jf * 16 + lr];
            const int rb = (jf * 16 + lr) * 64;
            f32x4 s = (f32x4){0.f, 0.f, 0.f, 0.f};
#pragma unroll
            for (int kt = 0; kt < 2; ++kt) {
                const int o = rb + ((kt * 32 + lo8) ^ swl);
                bf16x8 kh = *(const bf16x8*)(kp0 + o);
                bf16x8 km = *(const bf16x8*)(kp1 + o);
                bf16x8 kl = *(const bf16x8*)(kp2 + o);
                s = __builtin_amdgcn_mfma_f32_16x16x32_bf16(aQh[kt], kh, s, 0, 0, 0);
                s = __builtin_amdgcn_mfma_f32_16x16x32_bf16(aQh[kt], km, s, 0, 0, 0);
                s = __builtin_amdgcn_mfma_f32_16x16x32_bf16(aQm[kt], kh, s, 0, 0, 0);
                s = __builtin_amdgcn_mfma_f32_16x16x32_bf16(aQm[kt], km, s, 0, 0, 0);
                s = __builtin_amdgcn_mfma_f32_16x16x32_bf16(aQh[kt], kl, s, 0, 0, 0);
                s = __builtin_amdgcn_mfma_f32_16x16x32_bf16(aQl[kt], kh, s, 0, 0, 0);
            }
            sf[jf] = s;
        }

        // ---- xy -> W via arcosh form (division-free, 3 transcendentals)
#pragma unroll
        for (int jf = 0; jf < 4; ++jf) {
            const float y2 = y2v[jf];
            const float rb_ = rbv[jf];
#pragma unroll
            for (int r = 0; r < 4; ++r) {
                float xy = sf[jf][r];
                float sxy = x2r[r] + y2;
                float u = fmaf(-2.f, xy, sxy);           // ||x-y||^2
                float krr = Pr[r] * rb_;                 // 2c*ra*rb
                float z = fmaxf(fmaf(krr, u, 1.f), 1.f);
                float zm = fmaxf(fmaf(z, z, -1.f), 0.f);
                float lg2 = __builtin_amdgcn_logf(z + __builtin_amdgcn_sqrtf(zm));
                float wv_ = __builtin_amdgcn_exp2f(c2h * (lg2 * lg2));
                sf[jf][r] = wv_;
                den[r] = fmaf(wv_, gm1v[jf], den[r]);
            }
        }

#pragma unroll
        for (int r = 0; r < 4; ++r) {
            const int row = lg * 4 + r;
            const int sw = (row & 7) << 3;
#pragma unroll
            for (int jf = 0; jf < 4; ++jf) {
                const int colu = (jf * 16 + lr) ^ sw;
                float wv_ = sf[jf][r];
                u16 hb = bf16_rne(wv_);
                wbh[row * 64 + colu] = hb;
                wbl[row * 64 + colu] = bf16_rne(wv_ - bf16_tof(hb));
            }
        }

        __syncthreads();   // V staged (vmcnt drained); K prefetch also landed

        bf16x8 aWh[2], aWl[2];
#pragma unroll
        for (int kt = 0; kt < 2; ++kt) {
            const int colu = (kt * 32 + lo8) ^ swl;
            aWh[kt] = *(const bf16x8*)(wbh + lr * 64 + colu);
            aWl[kt] = *(const bf16x8*)(wbl + lr * 64 + colu);
        }

#pragma unroll
        for (int hf = 0; hf < 4; ++hf) {
            const int rb = (hf * 16 + lr) * 64;
#pragma unroll
            for (int kt = 0; kt < 2; ++kt) {
                const int o = rb + ((kt * 32 + lo8) ^ swl);
                bf16x8 vh = *(const bf16x8*)(&Vst[0][o]);
                bf16x8 vl = *(const bf16x8*)(&Vst[1][o]);
                pv[hf] = __builtin_amdgcn_mfma_f32_16x16x32_bf16(aWh[kt], vh, pv[hf], 0, 0, 0);
                pv[hf] = __builtin_amdgcn_mfma_f32_16x16x32_bf16(aWh[kt], vl, pv[hf], 0, 0, 0);
                pv[hf] = __builtin_amdgcn_mfma_f32_16x16x32_bf16(aWl[kt], vh, pv[hf], 0, 0, 0);
            }
        }

        __syncthreads();
        cur ^= 1;
    }

#pragma unroll
    for (int r = 0; r < 4; ++r) {
        float d = den[r];
#pragma unroll
        for (int msk = 1; msk < 16; msk <<= 1) d += __shfl_xor(d, msk, 64);
        float rd = 1.f / d;                      // den > 0 always (gamma-1 >= 1)
        float o_[4];
        float n2 = 0.f;
#pragma unroll
        for (int hf = 0; hf < 4; ++hf) { o_[hf] = pv[hf][r] * rd; n2 = fmaf(o_[hf], o_[hf], n2); }
#pragma unroll
        for (int msk = 1; msk < 16; msk <<= 1) n2 += __shfl_xor(n2, msk, 64);
        float nrm = sqrtf(fmaxf(n2, 1e-15f));
        float arg = fminf(sc * nrm, 1.f - 1e-7f);
        float t = artanh_fast(arg);
        float f = 0.5f * t / (sc * nrm);
        const int nrow = qt * 64 + w * 16 + lg * 4 + r;
        const size_t dst = ((size_t)(b * 576 + nrow)) * 768 + h * 64;
#pragma unroll
        for (int hf = 0; hf < 4; ++hf) {
            float val = o_[hf] * f;
            u16 hb = bf16_rne(val);
            Oh[dst + hf * 16 + lr] = hb;
            Ol[dst + hf * 16 + lr] = bf16_rne(val - bf16_tof(hb));
        }
    }
}

// ---------------- launcher ----------------
extern "C" void kernel_launch(void* const* d_in, const int* in_sizes, int n_in,
                              void* d_out, int out_size, void* d_ws, size_t ws_size,
                              hipStream_t stream) {
    (void)in_sizes; (void)n_in; (void)out_size; (void)ws_size;
    const float* x    = (const float*)d_in[0];
    const float* Wq   = (const float*)d_in[1];
    const float* bq   = (const float*)d_in[2];
    const float* Wk   = (const float*)d_in[3];
    const float* bk   = (const float*)d_in[4];
    const float* Wv   = (const float*)d_in[5];
    const float* bv   = (const float*)d_in[6];
    const float* Wo   = (const float*)d_in[7];
    const float* bo   = (const float*)d_in[8];
    const float* cent = (const float*)d_in[9];
    const float* curv = (const float*)d_in[10];
    const float* sigr = (const float*)d_in[11];
    float* out = (float*)d_out;

    const size_t QH  = (size_t)B_ * H_ * N_ * 64;   // 7,077,888 (also K/V token size)
    const size_t CK  = (size_t)H_ * M_ * 64;        // 98,304 centroid-plane size
    const size_t WSZ = (size_t)D_ * D_;             // 589,824

    float* fp = (float*)d_ws;
    float* x2q  = fp;            fp += (size_t)B_ * H_ * N_;
    float* y2g  = fp;            fp += (size_t)B_ * H_ * N_;
    float* gm1  = fp;            fp += (size_t)B_ * H_ * N_;
    float* rbjv = fp;            fp += (size_t)B_ * H_ * N_;
    float* y2c  = fp;            fp += (size_t)H_ * M_;
    float* gm1c = fp;            fp += (size_t)H_ * M_;
    float* rbcv = fp;            fp += (size_t)H_ * M_;
    u16* up = (u16*)fp;
    u16* xh  = up;  up += QH;     // aliased with Oh (xh dead before attn writes Oh)
    u16* xl  = up;  up += QH;     // aliased with Ol
    u16* Oh  = xh;
    u16* Ol  = xl;
    u16* Wqh = up;  up += WSZ;
    u16* Wql = up;  up += WSZ;
    u16* Wkh = up;  up += WSZ;
    u16* Wkl = up;  up += WSZ;
    u16* Wvh = up;  up += WSZ;
    u16* Wvl = up;  up += WSZ;
    u16* Woh = up;  up += WSZ;
    u16* Wol = up;  up += WSZ;
    u16* Qb  = up;  up += 3 * QH;
    u16* Kb  = up;  up += 3 * QH;
    u16* gV  = up;  up += 2 * QH;
    u16* Kc  = up;  up += 3 * CK;
    u16* gVc = up;  up += 2 * CK;

    u16* Qb0 = Qb;           u16* Qb1 = Qb + QH;   u16* Qb2 = Qb + 2 * QH;
    u16* Kb0 = Kb;           u16* Kb1 = Kb + QH;   u16* Kb2 = Kb + 2 * QH;
    u16* gV0 = gV;           u16* gV1 = gV + QH;
    u16* Kc0 = Kc;           u16* Kc1 = Kc + CK;   u16* Kc2 = Kc + 2 * CK;
    u16* gVc0 = gVc;         u16* gVc1 = gVc + CK;

    // 0: hi/lo splits (x + all 4 weights)
    split_bf16_kernel<<<(int)(QH / 4 / 256), 256, 0, stream>>>(x, xh, xl, (int)(QH / 4));
    split_w4_kernel<<<dim3((int)(WSZ / 4 / 256), 4), 256, 0, stream>>>(
        Wq, Wk, Wv, Wo, Wqh, Wql, Wkh, Wkl, Wvh, Wvl, Woh, Wol);

    // 2: per-head centroid maps (independent of GEMM)
    cent_kernel<<<24, 256, 0, stream>>>(cent, Kc0, Kc1, Kc2, gVc0, gVc1, y2c, gm1c, rbcv, curv);

    // 1: QKV projections + fused hyperbolic maps (MFMA, 128x256 tile, XCD-banded)
    gemm_qkv_mfma<<<648, 256, 0, stream>>>(xh, xl, Wqh, Wql, Wkh, Wkl, Wvh, Wvl,
                                           bq, bk, bv,
                                           Qb0, Qb1, Qb2, Kb0, Kb1, Kb2, gV0, gV1,
                                           x2q, y2g, gm1, rbjv, curv);
    // 4: fused attention (MFMA, LDS-staged, XCD-affine, arcosh logit)
    attn_kernel<<<1728, 256, 0, stream>>>(Qb0, Qb1, Qb2, Kb0, Kb1, Kb2, Kc0, Kc1, Kc2,
                                          gV0, gV1, gVc0, gVc1,
                                          x2q, y2g, gm1, y2c, gm1c, rbjv, rbcv,
                                          sigr, curv, Oh, Ol);
    // 5: output projection (MFMA, XCD-banded, pipelined)
    gemm_o_mfma<<<432, 256, 0, stream>>>(Oh, Ol, Woh, Wol, bo, out);
}

// Round 14
// 372.257 us; speedup vs baseline: 1.1181x; 1.1181x over previous
//
#include <hip/hip_runtime.h>
#include <cstdint>
#include <cstddef>

#define B_  16
#define N_  576
#define D_  768
#define H_  12
#define HD_ 64
#define M_  128
#define J_  704   // N_ + M_

typedef unsigned short u16;
typedef __attribute__((ext_vector_type(8))) short bf16x8;
typedef __attribute__((ext_vector_type(4))) float f32x4;
typedef __attribute__((ext_vector_type(4))) unsigned short u16x4;
typedef __attribute__((ext_vector_type(8))) unsigned short u16x8;

// ---------------- helpers ----------------

__device__ __forceinline__ float softplus_f(float x) {
    return (x > 20.f) ? x : log1pf(expf(x));
}

__device__ __forceinline__ float wred_sum64(float v) {
#pragma unroll
    for (int m = 1; m < 64; m <<= 1) v += __shfl_xor(v, m, 64);
    return v;
}

__device__ __forceinline__ u16 bf16_rne(float f) {
    unsigned int u = __float_as_uint(f);
    unsigned int r = u + 0x7FFFu + ((u >> 16) & 1u);
    return (u16)(r >> 16);
}
__device__ __forceinline__ float bf16_tof(u16 h) {
    return __uint_as_float(((unsigned int)h) << 16);
}

// expmap0 total multiplier (division- and tanhf-free: v_rcp/v_exp).
__device__ __forceinline__ float expmap0_factor(float n2, float sc, float* n2out) {
    const float ATANH_1M1E5 = 6.1030335f;     // artanh(1 - 1e-5)
    const float LOG2E2 = 2.8853900817779268f; // 2*log2(e)
    float rsc = __builtin_amdgcn_rcpf(sc);
    float n0 = __builtin_amdgcn_sqrtf(fmaxf(n2, 1e-15f));
    float f1 = fminf(1.f, (ATANH_1M1E5 * rsc) * __builtin_amdgcn_rcpf(n0));  // pre-clip
    float n1 = n0 * f1;
    float a  = sc * n1;
    float e2a = __builtin_amdgcn_exp2f(a * LOG2E2);
    float th  = 1.f - 2.f * __builtin_amdgcn_rcpf(e2a + 1.f);   // tanh(a), a not tiny
    float yfac  = th * __builtin_amdgcn_rcpf(a);
    float f2 = fminf(1.f, 0.99999f * __builtin_amdgcn_rcpf(th)); // post-clip
    float fn = (th * rsc) * f2;
    *n2out = fn * fn;
    return f1 * yfac * f2;
}

__device__ __forceinline__ float artanh_fast(float z) {  // z in [0, 1-1e-7]
    return 0.5f * __logf((1.f + z) / (1.f - z));
}

// global -> LDS direct copy, 16B per lane (wave-uniform LDS base + lane*16)
typedef const __attribute__((address_space(1))) unsigned int* gas_u32;
typedef __attribute__((address_space(3))) unsigned int* las_u32;
__device__ __forceinline__ void gload_lds16(const u16* g, u16* l) {
    __builtin_amdgcn_global_load_lds((gas_u32)(const void*)g, (las_u32)(void*)l, 16, 0, 0);
}

// ---------------- kernel 0a: f32 -> bf16 hi/lo split (x) ----------------
__global__ __launch_bounds__(256) void split_bf16_kernel(
    const float* __restrict__ src, u16* __restrict__ hi, u16* __restrict__ lo, int n4)
{
    int i = blockIdx.x * 256 + threadIdx.x;
    if (i >= n4) return;
    float4 v = ((const float4*)src)[i];
    u16x4 h, l;
    h[0] = bf16_rne(v.x); l[0] = bf16_rne(v.x - bf16_tof(h[0]));
    h[1] = bf16_rne(v.y); l[1] = bf16_rne(v.y - bf16_tof(h[1]));
    h[2] = bf16_rne(v.z); l[2] = bf16_rne(v.z - bf16_tof(h[2]));
    h[3] = bf16_rne(v.w); l[3] = bf16_rne(v.w - bf16_tof(h[3]));
    ((u16x4*)hi)[i] = h;
    ((u16x4*)lo)[i] = l;
}

// ---------------- kernel 0b: split all 4 weight matrices in one launch ----------------
__global__ __launch_bounds__(256) void split_w4_kernel(
    const float* __restrict__ W0, const float* __restrict__ W1,
    const float* __restrict__ W2, const float* __restrict__ W3,
    u16* __restrict__ H0, u16* __restrict__ L0, u16* __restrict__ H1, u16* __restrict__ L1,
    u16* __restrict__ H2, u16* __restrict__ L2, u16* __restrict__ H3, u16* __restrict__ L3)
{
    int i = blockIdx.x * 256 + threadIdx.x;   // < WSZ/4 = 147456
    const int wsel = blockIdx.y;
    const float* src = wsel == 0 ? W0 : (wsel == 1 ? W1 : (wsel == 2 ? W2 : W3));
    u16* hi = wsel == 0 ? H0 : (wsel == 1 ? H1 : (wsel == 2 ? H2 : H3));
    u16* lo = wsel == 0 ? L0 : (wsel == 1 ? L1 : (wsel == 2 ? L2 : L3));
    float4 v = ((const float4*)src)[i];
    u16x4 h, l;
    h[0] = bf16_rne(v.x); l[0] = bf16_rne(v.x - bf16_tof(h[0]));
    h[1] = bf16_rne(v.y); l[1] = bf16_rne(v.y - bf16_tof(h[1]));
    h[2] = bf16_rne(v.z); l[2] = bf16_rne(v.z - bf16_tof(h[2]));
    h[3] = bf16_rne(v.w); l[3] = bf16_rne(v.w - bf16_tof(h[3]));
    ((u16x4*)hi)[i] = h;
    ((u16x4*)lo)[i] = l;
}

// ---------------- kernel 1: QKV projection + FUSED hyperbolic maps ----------------
// Double-buffered LDS, ONE barrier per K-step:
//   read frags(cur) -> STAGE(next -> cur^1) -> MFMA(cur) -> barrier.
__global__ __launch_bounds__(256) void gemm_qkv_mfma(
    const u16* __restrict__ xh, const u16* __restrict__ xl,
    const u16* __restrict__ Wh0, const u16* __restrict__ Wl0,
    const u16* __restrict__ Wh1, const u16* __restrict__ Wl1,
    const u16* __restrict__ Wh2, const u16* __restrict__ Wl2,
    const float* __restrict__ bq, const float* __restrict__ bk, const float* __restrict__ bv,
    u16* __restrict__ Qb0, u16* __restrict__ Qb1, u16* __restrict__ Qb2,
    u16* __restrict__ Kb0, u16* __restrict__ Kb1, u16* __restrict__ Kb2,
    u16* __restrict__ gV0, u16* __restrict__ gV1,
    float* __restrict__ x2q, float* __restrict__ y2g, float* __restrict__ gm1,
    float* __restrict__ rbj,
    const float* __restrict__ curv_raw)
{
    __shared__ u16 Ah[2][4096], Al[2][4096], Bh[2][4096], Bl[2][4096];   // dbuf
    const int tid = threadIdx.x;
    const int w = tid >> 6, lane = tid & 63;
    const int wr = w >> 1, wc = w & 1;
    const int lrow = lane & 15, lk8 = (lane >> 4) << 3;
    const int lg = lane >> 4;
    // XCD-band swizzle: 1296 blocks = 8 XCDs x (9 mt x 18 yb)
    const int bid = blockIdx.x;
    const int xcd = bid & 7, ser = bid >> 3;       // ser < 162
    const int mt = xcd * 9 + (ser % 9);
    const int yb = ser / 9;                        // < 18
    const int which = yb / 6, ct = yb - which * 6;
    const u16* Bp_h = which == 0 ? Wh0 : (which == 1 ? Wh1 : Wh2);
    const u16* Bp_l = which == 0 ? Wl0 : (which == 1 ? Wl1 : Wl2);
    const int row0 = mt * 128, col0 = ct * 128;

    const size_t a0 = (size_t)(row0 + (2 * w + 0) * 16 + lrow) * 768 + lk8;
    const size_t a1 = a0 + 16 * 768;
    const size_t b0 = (size_t)(col0 + (2 * w + 0) * 16 + lrow) * 768 + lk8;
    const size_t b1 = b0 + 16 * 768;
    const int wo = (2 * w) * 512;

    auto STAGE = [&](int k0, int buf) {
        gload_lds16(xh + a0 + k0, &Ah[buf][wo]);
        gload_lds16(xh + a1 + k0, &Ah[buf][wo + 512]);
        gload_lds16(xl + a0 + k0, &Al[buf][wo]);
        gload_lds16(xl + a1 + k0, &Al[buf][wo + 512]);
        gload_lds16(Bp_h + b0 + k0, &Bh[buf][wo]);
        gload_lds16(Bp_h + b1 + k0, &Bh[buf][wo + 512]);
        gload_lds16(Bp_l + b0 + k0, &Bl[buf][wo]);
        gload_lds16(Bp_l + b1 + k0, &Bl[buf][wo + 512]);
    };

    f32x4 acc[4][4];
#pragma unroll
    for (int i = 0; i < 4; ++i)
#pragma unroll
        for (int j = 0; j < 4; ++j) acc[i][j] = (f32x4){0.f, 0.f, 0.f, 0.f};

    STAGE(0, 0);
    __syncthreads();

    const int lo8 = lane * 8;
    int cur = 0;
    for (int k0 = 0; k0 < 768; k0 += 32) {
        bf16x8 aH[4], aL[4], bH[4], bL[4];
#pragma unroll
        for (int i = 0; i < 4; ++i) {
            aH[i] = *(const bf16x8*)(&Ah[cur][(wr * 4 + i) * 512 + lo8]);
            aL[i] = *(const bf16x8*)(&Al[cur][(wr * 4 + i) * 512 + lo8]);
            bH[i] = *(const bf16x8*)(&Bh[cur][(wc * 4 + i) * 512 + lo8]);
            bL[i] = *(const bf16x8*)(&Bl[cur][(wc * 4 + i) * 512 + lo8]);
        }
        if (k0 < 736) STAGE(k0 + 32, cur ^ 1);   // fills other buffer; drains at barrier
#pragma unroll
        for (int mi = 0; mi < 4; ++mi)
#pragma unroll
            for (int ni = 0; ni < 4; ++ni) {
                acc[mi][ni] = __builtin_amdgcn_mfma_f32_16x16x32_bf16(aH[mi], bH[ni], acc[mi][ni], 0, 0, 0);
                acc[mi][ni] = __builtin_amdgcn_mfma_f32_16x16x32_bf16(aH[mi], bL[ni], acc[mi][ni], 0, 0, 0);
                acc[mi][ni] = __builtin_amdgcn_mfma_f32_16x16x32_bf16(aL[mi], bH[ni], acc[mi][ni], 0, 0, 0);
            }
        __syncthreads();                          // one barrier per K-step
        cur ^= 1;
    }

    // ---------------- fused epilogue ----------------
    const float* bias = which == 0 ? bq : (which == 1 ? bk : bv);
    const int h = ct * 2 + wc;
    const int rbase = row0 + wr * 64 + (lg << 2);
    const float c  = softplus_f(curv_raw[0]);
    const float sc = sqrtf(c);
    float bvv[4];
#pragma unroll
    for (int ni = 0; ni < 4; ++ni) bvv[ni] = bias[h * 64 + ni * 16 + lrow];

#pragma unroll
    for (int mi = 0; mi < 4; ++mi) {
        float v4[4][4];   // [ni][r]
#pragma unroll
        for (int ni = 0; ni < 4; ++ni) {
            f32x4 a = acc[mi][ni];
#pragma unroll
            for (int r = 0; r < 4; ++r) v4[ni][r] = a[r] + bvv[ni];
        }
        // per-row sumsq: in-lane ni-sum first, then 4-step lrow butterfly
        float f_[4], n2o_[4];
#pragma unroll
        for (int r = 0; r < 4; ++r) {
            float s = v4[0][r] * v4[0][r];
#pragma unroll
            for (int ni = 1; ni < 4; ++ni) s = fmaf(v4[ni][r], v4[ni][r], s);
#pragma unroll
            for (int m = 1; m < 16; m <<= 1) s += __shfl_xor(s, m, 64);
            f_[r] = expmap0_factor(s, sc, &n2o_[r]);
        }
        const int row0g = rbase + mi * 16;          // 4 consecutive rows, same batch
        const int bb = row0g / 576;
        const int nn0 = row0g - bb * 576;
        const size_t gbase = ((size_t)(bb * 12 + h)) * 576 + nn0;
        if (which == 2) {
            float gmm[4];
#pragma unroll
            for (int r = 0; r < 4; ++r)
                gmm[r] = 2.f * __builtin_amdgcn_rcpf(fmaxf(1.f - c * n2o_[r], 1e-15f));
            if (lrow == 0) {
#pragma unroll
                for (int r = 0; r < 4; ++r) gm1[gbase + r] = gmm[r] - 1.f;
            }
#pragma unroll
            for (int ni = 0; ni < 4; ++ni) {
                const int hd = ni * 16 + lrow;
                u16x4 hs, ls;
#pragma unroll
                for (int r = 0; r < 4; ++r) {
                    float gv = v4[ni][r] * f_[r] * gmm[r];
                    u16 hb = bf16_rne(gv);
                    hs[r] = hb;
                    ls[r] = bf16_rne(gv - bf16_tof(hb));
                }
                const size_t dst = (((size_t)(bb * 12 + h)) * 64 + hd) * 576 + nn0;
                *(u16x4*)(gV0 + dst) = hs;
                *(u16x4*)(gV1 + dst) = ls;
            }
        } else {
            float* scal = which == 0 ? x2q : y2g;
            if (lrow == 0) {
#pragma unroll
                for (int r = 0; r < 4; ++r) scal[gbase + r] = n2o_[r];
                if (which == 1) {
#pragma unroll
                    for (int r = 0; r < 4; ++r)
                        rbj[gbase + r] = __builtin_amdgcn_rcpf(fmaf(-c, n2o_[r], 1.f));
                }
            }
            u16* P0 = which == 0 ? Qb0 : Kb0;
            u16* P1 = which == 0 ? Qb1 : Kb1;
            u16* P2 = which == 0 ? Qb2 : Kb2;
#pragma unroll
            for (int ni = 0; ni < 4; ++ni) {
                const int hd = ni * 16 + lrow;
#pragma unroll
                for (int r = 0; r < 4; ++r) {
                    float y = v4[ni][r] * f_[r];
                    u16 hb = bf16_rne(y);
                    float r1 = y - bf16_tof(hb);
                    u16 mb = bf16_rne(r1);
                    u16 lb2 = bf16_rne(r1 - bf16_tof(mb));
                    const size_t off = (gbase + r) * 64 + hd;
                    P0[off] = hb; P1[off] = mb; P2[off] = lb2;
                }
            }
        }
    }
}

// ---------------- kernel 5: output projection (dbuf, one barrier per K-step) ----------------
__global__ __launch_bounds__(256) void gemm_o_mfma(
    const u16* __restrict__ Oh, const u16* __restrict__ Ol,
    const u16* __restrict__ Wh, const u16* __restrict__ Wl,
    const float* __restrict__ bo, float* __restrict__ out)
{
    __shared__ u16 Ah[2][4096], Al[2][4096], Bh[2][4096], Bl[2][4096];
    const int tid = threadIdx.x;
    const int w = tid >> 6, lane = tid & 63;
    const int wr = w >> 1, wc = w & 1;
    const int lrow = lane & 15, lk8 = (lane >> 4) << 3;
    // 432 blocks = 8 XCDs x (9 mt x 6 ct)
    const int bid = blockIdx.x;
    const int xcd = bid & 7, ser = bid >> 3;       // ser < 54
    const int mt = xcd * 9 + (ser % 9);
    const int ct = ser / 9;                        // < 6
    const int row0 = mt * 128, col0 = ct * 128;

    const size_t a0 = (size_t)(row0 + (2 * w + 0) * 16 + lrow) * 768 + lk8;
    const size_t a1 = a0 + 16 * 768;
    const size_t b0 = (size_t)(col0 + (2 * w + 0) * 16 + lrow) * 768 + lk8;
    const size_t b1 = b0 + 16 * 768;
    const int wo = (2 * w) * 512;

    auto STAGE = [&](int k0, int buf) {
        gload_lds16(Oh + a0 + k0, &Ah[buf][wo]);
        gload_lds16(Oh + a1 + k0, &Ah[buf][wo + 512]);
        gload_lds16(Ol + a0 + k0, &Al[buf][wo]);
        gload_lds16(Ol + a1 + k0, &Al[buf][wo + 512]);
        gload_lds16(Wh + b0 + k0, &Bh[buf][wo]);
        gload_lds16(Wh + b1 + k0, &Bh[buf][wo + 512]);
        gload_lds16(Wl + b0 + k0, &Bl[buf][wo]);
        gload_lds16(Wl + b1 + k0, &Bl[buf][wo + 512]);
    };

    f32x4 acc[4][4];
#pragma unroll
    for (int i = 0; i < 4; ++i)
#pragma unroll
        for (int j = 0; j < 4; ++j) acc[i][j] = (f32x4){0.f, 0.f, 0.f, 0.f};

    STAGE(0, 0);
    __syncthreads();

    const int lo8 = lane * 8;
    int cur = 0;
    for (int k0 = 0; k0 < 768; k0 += 32) {
        bf16x8 aH[4], aL[4], bH[4], bL[4];
#pragma unroll
        for (int i = 0; i < 4; ++i) {
            aH[i] = *(const bf16x8*)(&Ah[cur][(wr * 4 + i) * 512 + lo8]);
            aL[i] = *(const bf16x8*)(&Al[cur][(wr * 4 + i) * 512 + lo8]);
            bH[i] = *(const bf16x8*)(&Bh[cur][(wc * 4 + i) * 512 + lo8]);
            bL[i] = *(const bf16x8*)(&Bl[cur][(wc * 4 + i) * 512 + lo8]);
        }
        if (k0 < 736) STAGE(k0 + 32, cur ^ 1);
#pragma unroll
        for (int mi = 0; mi < 4; ++mi)
#pragma unroll
            for (int ni = 0; ni < 4; ++ni) {
                acc[mi][ni] = __builtin_amdgcn_mfma_f32_16x16x32_bf16(aH[mi], bH[ni], acc[mi][ni], 0, 0, 0);
                acc[mi][ni] = __builtin_amdgcn_mfma_f32_16x16x32_bf16(aH[mi], bL[ni], acc[mi][ni], 0, 0, 0);
                acc[mi][ni] = __builtin_amdgcn_mfma_f32_16x16x32_bf16(aL[mi], bH[ni], acc[mi][ni], 0, 0, 0);
            }
        __syncthreads();
        cur ^= 1;
    }

    const int rbase = row0 + wr * 64 + ((lane >> 4) << 2);
#pragma unroll
    for (int ni = 0; ni < 4; ++ni) {
        const int colg = col0 + wc * 64 + ni * 16 + lrow;
        const float bv_ = bo[colg];
#pragma unroll
        for (int mi = 0; mi < 4; ++mi) {
            f32x4 a = acc[mi][ni];
#pragma unroll
            for (int r = 0; r < 4; ++r) {
                int row = rbase + mi * 16 + r;
                out[(size_t)row * 768 + colg] = a[r] + bv_;
            }
        }
    }
}

// ---------------- kernel 2: per-head centroid maps (once, shared across batch) ----------------
__global__ __launch_bounds__(256) void cent_kernel(
    const float* __restrict__ cent,
    u16* __restrict__ Kc0, u16* __restrict__ Kc1, u16* __restrict__ Kc2,
    u16* __restrict__ gVc0, u16* __restrict__ gVc1,
    float* __restrict__ y2c, float* __restrict__ gm1c, float* __restrict__ rbc,
    const float* __restrict__ curv_raw)
{
    __shared__ float gvt_s[64][65];
    const float c  = softplus_f(curv_raw[0]);
    const float sc = sqrtf(c);
    const int t = blockIdx.x;         // < 24
    const int h = t >> 1, ct = t & 1;
    const int w = threadIdx.x >> 6, lane = threadIdx.x & 63;
#pragma unroll 4
    for (int i = 0; i < 16; ++i) {
        const int m = ct * 64 + w * 16 + i;
        const size_t g = (size_t)h * 128 + m;
        float cv = cent[g * 64 + lane];
        float n2 = wred_sum64(cv * cv);
        float n2o;
        float f = expmap0_factor(n2, sc, &n2o);
        float ky = cv * f;
        u16 kh = bf16_rne(ky);
        float r1 = ky - bf16_tof(kh);
        u16 km = bf16_rne(r1);
        u16 kl = bf16_rne(r1 - bf16_tof(km));
        Kc0[g * 64 + lane] = kh; Kc1[g * 64 + lane] = km; Kc2[g * 64 + lane] = kl;
        float gmm = 2.f * __builtin_amdgcn_rcpf(fmaxf(1.f - c * n2o, 1e-15f));
        gvt_s[lane][w * 16 + i] = ky * gmm;
        if (lane == 0) {
            y2c[g] = n2o; gm1c[g] = gmm - 1.f;
            rbc[g] = __builtin_amdgcn_rcpf(fmaf(-c, n2o, 1.f));
        }
    }
    __syncthreads();
    const int hd = threadIdx.x >> 2, j0 = (threadIdx.x & 3) * 16;
    u16 hb[16], lb[16];
#pragma unroll
    for (int e = 0; e < 16; ++e) {
        float v = gvt_s[hd][j0 + e];
        hb[e] = bf16_rne(v);
        lb[e] = bf16_rne(v - bf16_tof(hb[e]));
    }
    const size_t dst = ((size_t)h * 64 + hd) * 128 + ct * 64 + j0;
    *(u16x8*)(gVc0 + dst)     = *(u16x8*)&hb[0];
    *(u16x8*)(gVc0 + dst + 8) = *(u16x8*)&hb[8];
    *(u16x8*)(gVc1 + dst)     = *(u16x8*)&lb[0];
    *(u16x8*)(gVc1 + dst + 8) = *(u16x8*)&lb[8];
}

// ---------------- kernel 4: fused hyperbolic attention (MFMA, LDS-staged K/V) ----------------
// Logit via the arcosh form of the Poincare distance (exactly 2*artanh(arg)):
// z = 1 + 2c*||x-y||^2 * ra * rb; W = exp2(c2h*lg^2), lg = log2(z + sqrt(z^2-1)).
__global__ __launch_bounds__(256) void attn_kernel(
    const u16* __restrict__ Qb0, const u16* __restrict__ Qb1, const u16* __restrict__ Qb2,
    const u16* __restrict__ Kb0, const u16* __restrict__ Kb1, const u16* __restrict__ Kb2,
    const u16* __restrict__ Kc0, const u16* __restrict__ Kc1, const u16* __restrict__ Kc2,
    const u16* __restrict__ gV0, const u16* __restrict__ gV1,
    const u16* __restrict__ gVc0, const u16* __restrict__ gVc1,
    const float* __restrict__ x2q, const float* __restrict__ y2g, const float* __restrict__ gm1,
    const float* __restrict__ y2c, const float* __restrict__ gm1c,
    const float* __restrict__ rbj, const float* __restrict__ rbc,
    const float* __restrict__ sigma_raw, const float* __restrict__ curv_raw,
    u16* __restrict__ Oh, u16* __restrict__ Ol)
{
    __shared__ __align__(16) u16 Kst[2][3][4096];  // [buf][plane][row*64 + swizzled col]
    __shared__ __align__(16) u16 Vst[2][4096];     // [plane][row*64 + swizzled col]
    __shared__ __align__(16) u16 wb_hi[4][1024];
    __shared__ __align__(16) u16 wb_lo[4][1024];

    const int blk = blockIdx.x;
    const int xcd = blk & 7;
    const int serial = blk >> 3;
    const int bhg = serial / 9;
    const int qt = serial - bhg * 9;
    const int bh = bhg * 8 + xcd;
    const int b = bh / 12, h = bh % 12;
    const float c  = softplus_f(curv_raw[0]);
    const float sc = sqrtf(c);
    const float sig = softplus_f(sigma_raw[h]) + 1e-6f;
    const float coef = -2.f / (c * sig * sig);   // logit = coef * artanh(arg)^2
    const float c2h  = coef * 0.25f * 0.6931471805599453f;  // exp2 basis

    const int tid = threadIdx.x;
    const int w = tid >> 6, lane = tid & 63;
    const int lr = lane & 15, lg = lane >> 4, lo8 = lg * 8;
    const int swl = (lr & 7) << 3;

    const size_t qbase = (size_t)bh * 576 + qt * 64;

    int srow[2], scol[2];
#pragma unroll
    for (int rr = 0; rr < 2; ++rr) {
        int cch = (rr * 4 + w) * 64 + lane;
        srow[rr] = cch >> 3;
        scol[rr] = ((cch & 7) ^ (srow[rr] & 7)) << 3;
    }
    const size_t kb_base = (size_t)bh * 576 * 64;
    const size_t kc_base = (size_t)h * 128 * 64;
    const size_t vb_base = (size_t)bh * 64 * 576;
    const size_t vc_base = (size_t)h * 64 * 128;

    auto stageK = [&](int t, int buf) {
        if (t < 9) {
            const size_t rb = kb_base + (size_t)t * 64 * 64;
#pragma unroll
            for (int rr = 0; rr < 2; ++rr) {
                const size_t so = rb + (size_t)srow[rr] * 64 + scol[rr];
                gload_lds16(Kb0 + so, &Kst[buf][0][(rr * 4 + w) * 512]);
                gload_lds16(Kb1 + so, &Kst[buf][1][(rr * 4 + w) * 512]);
                gload_lds16(Kb2 + so, &Kst[buf][2][(rr * 4 + w) * 512]);
            }
        } else {
            const size_t rb = kc_base + (size_t)(t - 9) * 64 * 64;
#pragma unroll
            for (int rr = 0; rr < 2; ++rr) {
                const size_t so = rb + (size_t)srow[rr] * 64 + scol[rr];
                gload_lds16(Kc0 + so, &Kst[buf][0][(rr * 4 + w) * 512]);
                gload_lds16(Kc1 + so, &Kst[buf][1][(rr * 4 + w) * 512]);
                gload_lds16(Kc2 + so, &Kst[buf][2][(rr * 4 + w) * 512]);
            }
        }
    };
    auto stageV = [&](int t) {
        if (t < 9) {
            const size_t rb = vb_base + (size_t)t * 64;
#pragma unroll
            for (int rr = 0; rr < 2; ++rr) {
                const size_t so = rb + (size_t)srow[rr] * 576 + scol[rr];
                gload_lds16(gV0 + so, &Vst[0][(rr * 4 + w) * 512]);
                gload_lds16(gV1 + so, &Vst[1][(rr * 4 + w) * 512]);
            }
        } else {
            const size_t rb = vc_base + (size_t)(t - 9) * 64;
#pragma unroll
            for (int rr = 0; rr < 2; ++rr) {
                const size_t so = rb + (size_t)srow[rr] * 128 + scol[rr];
                gload_lds16(gVc0 + so, &Vst[0][(rr * 4 + w) * 512]);
                gload_lds16(gVc1 + so, &Vst[1][(rr * 4 + w) * 512]);
            }
        }
    };

    bf16x8 aQh[2], aQm[2], aQl[2];
    {
        const size_t qrow = (qbase + w * 16 + lr) * 64;
#pragma unroll
        for (int kt = 0; kt < 2; ++kt) {
            const size_t o = qrow + kt * 32 + lo8;
            aQh[kt] = *(const bf16x8*)(Qb0 + o);
            aQm[kt] = *(const bf16x8*)(Qb1 + o);
            aQl[kt] = *(const bf16x8*)(Qb2 + o);
        }
    }
    float x2r[4], Pr[4];
#pragma unroll
    for (int r = 0; r < 4; ++r) {
        float x2 = x2q[qbase + w * 16 + lg * 4 + r];
        x2r[r] = x2;
        Pr[r] = (c + c) / fmaf(-c, x2, 1.f);    // 2c * ra, ra = 1/(1-c*x2)
    }

    f32x4 pv[4];
#pragma unroll
    for (int i = 0; i < 4; ++i) pv[i] = (f32x4){0.f, 0.f, 0.f, 0.f};
    float den[4] = {0.f, 0.f, 0.f, 0.f};

    u16* wbh = &wb_hi[w][0];
    u16* wbl = &wb_lo[w][0];

    stageK(0, 0);
    __syncthreads();

    int cur = 0;
    for (int jt = 0; jt < 11; ++jt) {
        const int jb = jt * 64;

        if (jt < 10) stageK(jt + 1, cur ^ 1);
        stageV(jt);

        const float* y2p;
        const float* gm1p;
        const float* rbp;
        if (jt < 9) {
            y2p = y2g + (size_t)bh * 576 + jb;  gm1p = gm1 + (size_t)bh * 576 + jb;
            rbp = rbj + (size_t)bh * 576 + jb;
        } else {
            y2p = y2c + (size_t)h * 128 + (jb - 576); gm1p = gm1c + (size_t)h * 128 + (jb - 576);
            rbp = rbc + (size_t)h * 128 + (jb - 576);
        }

        const u16* kp0 = &Kst[cur][0][0];
        const u16* kp1 = &Kst[cur][1][0];
        const u16* kp2 = &Kst[cur][2][0];
        f32x4 sf[4];
        float y2v[4], gm1v[4], rbv[4];
#pragma unroll
        for (int jf = 0; jf < 4; ++jf) {
            y2v[jf] = y2p[jf * 16 + lr];
            gm1v[jf] = gm1p[jf * 16 + lr];
            rbv[jf] = rbp[jf * 16 + lr];
            const int rb = (jf * 16 + lr) * 64;
            f32x4 s = (f32x4){0.f, 0.f, 0.f, 0.f};
#pragma unroll
            for (int kt = 0; kt < 2; ++kt) {
                const int o = rb + ((kt * 32 + lo8) ^ swl);
                bf16x8 kh = *(const bf16x8*)(kp0 + o);
                bf16x8 km = *(const bf16x8*)(kp1 + o);
                bf16x8 kl = *(const bf16x8*)(kp2 + o);
                s = __builtin_amdgcn_mfma_f32_16x16x32_bf16(aQh[kt], kh, s, 0, 0, 0);
                s = __builtin_amdgcn_mfma_f32_16x16x32_bf16(aQh[kt], km, s, 0, 0, 0);
                s = __builtin_amdgcn_mfma_f32_16x16x32_bf16(aQm[kt], kh, s, 0, 0, 0);
                s = __builtin_amdgcn_mfma_f32_16x16x32_bf16(aQm[kt], km, s, 0, 0, 0);
                s = __builtin_amdgcn_mfma_f32_16x16x32_bf16(aQh[kt], kl, s, 0, 0, 0);
                s = __builtin_amdgcn_mfma_f32_16x16x32_bf16(aQl[kt], kh, s, 0, 0, 0);
            }
            sf[jf] = s;
        }

        // ---- xy -> W via arcosh form (division-free, 3 transcendentals)
#pragma unroll
        for (int jf = 0; jf < 4; ++jf) {
            const float y2 = y2v[jf];
            const float rb_ = rbv[jf];
#pragma unroll
            for (int r = 0; r < 4; ++r) {
                float xy = sf[jf][r];
                float sxy = x2r[r] + y2;
                float u = fmaf(-2.f, xy, sxy);           // ||x-y||^2
                float krr = Pr[r] * rb_;                 // 2c*ra*rb
                float z = fmaxf(fmaf(krr, u, 1.f), 1.f);
                float zm = fmaxf(fmaf(z, z, -1.f), 0.f);
                float lg2 = __builtin_amdgcn_logf(z + __builtin_amdgcn_sqrtf(zm));
                float wv_ = __builtin_amdgcn_exp2f(c2h * (lg2 * lg2));
                sf[jf][r] = wv_;
                den[r] = fmaf(wv_, gm1v[jf], den[r]);
            }
        }

#pragma unroll
        for (int r = 0; r < 4; ++r) {
            const int row = lg * 4 + r;
            const int sw = (row & 7) << 3;
#pragma unroll
            for (int jf = 0; jf < 4; ++jf) {
                const int colu = (jf * 16 + lr) ^ sw;
                float wv_ = sf[jf][r];
                u16 hb = bf16_rne(wv_);
                wbh[row * 64 + colu] = hb;
                wbl[row * 64 + colu] = bf16_rne(wv_ - bf16_tof(hb));
            }
        }

        __syncthreads();   // V staged (vmcnt drained); K prefetch also landed

        bf16x8 aWh[2], aWl[2];
#pragma unroll
        for (int kt = 0; kt < 2; ++kt) {
            const int colu = (kt * 32 + lo8) ^ swl;
            aWh[kt] = *(const bf16x8*)(wbh + lr * 64 + colu);
            aWl[kt] = *(const bf16x8*)(wbl + lr * 64 + colu);
        }

#pragma unroll
        for (int hf = 0; hf < 4; ++hf) {
            const int rb = (hf * 16 + lr) * 64;
#pragma unroll
            for (int kt = 0; kt < 2; ++kt) {
                const int o = rb + ((kt * 32 + lo8) ^ swl);
                bf16x8 vh = *(const bf16x8*)(&Vst[0][o]);
                bf16x8 vl = *(const bf16x8*)(&Vst[1][o]);
                pv[hf] = __builtin_amdgcn_mfma_f32_16x16x32_bf16(aWh[kt], vh, pv[hf], 0, 0, 0);
                pv[hf] = __builtin_amdgcn_mfma_f32_16x16x32_bf16(aWh[kt], vl, pv[hf], 0, 0, 0);
                pv[hf] = __builtin_amdgcn_mfma_f32_16x16x32_bf16(aWl[kt], vh, pv[hf], 0, 0, 0);
            }
        }

        __syncthreads();
        cur ^= 1;
    }

#pragma unroll
    for (int r = 0; r < 4; ++r) {
        float d = den[r];
#pragma unroll
        for (int msk = 1; msk < 16; msk <<= 1) d += __shfl_xor(d, msk, 64);
        float rd = 1.f / d;                      // den > 0 always (gamma-1 >= 1)
        float o_[4];
        float n2 = 0.f;
#pragma unroll
        for (int hf = 0; hf < 4; ++hf) { o_[hf] = pv[hf][r] * rd; n2 = fmaf(o_[hf], o_[hf], n2); }
#pragma unroll
        for (int msk = 1; msk < 16; msk <<= 1) n2 += __shfl_xor(n2, msk, 64);
        float nrm = sqrtf(fmaxf(n2, 1e-15f));
        float arg = fminf(sc * nrm, 1.f - 1e-7f);
        float t = artanh_fast(arg);
        float f = 0.5f * t / (sc * nrm);
        const int nrow = qt * 64 + w * 16 + lg * 4 + r;
        const size_t dst = ((size_t)(b * 576 + nrow)) * 768 + h * 64;
#pragma unroll
        for (int hf = 0; hf < 4; ++hf) {
            float val = o_[hf] * f;
            u16 hb = bf16_rne(val);
            Oh[dst + hf * 16 + lr] = hb;
            Ol[dst + hf * 16 + lr] = bf16_rne(val - bf16_tof(hb));
        }
    }
}

// ---------------- launcher ----------------
extern "C" void kernel_launch(void* const* d_in, const int* in_sizes, int n_in,
                              void* d_out, int out_size, void* d_ws, size_t ws_size,
                              hipStream_t stream) {
    (void)in_sizes; (void)n_in; (void)out_size; (void)ws_size;
    const float* x    = (const float*)d_in[0];
    const float* Wq   = (const float*)d_in[1];
    const float* bq   = (const float*)d_in[2];
    const float* Wk   = (const float*)d_in[3];
    const float* bk   = (const float*)d_in[4];
    const float* Wv   = (const float*)d_in[5];
    const float* bv   = (const float*)d_in[6];
    const float* Wo   = (const float*)d_in[7];
    const float* bo   = (const float*)d_in[8];
    const float* cent = (const float*)d_in[9];
    const float* curv = (const float*)d_in[10];
    const float* sigr = (const float*)d_in[11];
    float* out = (float*)d_out;

    const size_t QH  = (size_t)B_ * H_ * N_ * 64;   // 7,077,888 (also K/V token size)
    const size_t CK  = (size_t)H_ * M_ * 64;        // 98,304 centroid-plane size
    const size_t WSZ = (size_t)D_ * D_;             // 589,824

    float* fp = (float*)d_ws;
    float* x2q  = fp;            fp += (size_t)B_ * H_ * N_;
    float* y2g  = fp;            fp += (size_t)B_ * H_ * N_;
    float* gm1  = fp;            fp += (size_t)B_ * H_ * N_;
    float* rbjv = fp;            fp += (size_t)B_ * H_ * N_;
    float* y2c  = fp;            fp += (size_t)H_ * M_;
    float* gm1c = fp;            fp += (size_t)H_ * M_;
    float* rbcv = fp;            fp += (size_t)H_ * M_;
    u16* up = (u16*)fp;
    u16* xh  = up;  up += QH;     // aliased with Oh (xh dead before attn writes Oh)
    u16* xl  = up;  up += QH;     // aliased with Ol
    u16* Oh  = xh;
    u16* Ol  = xl;
    u16* Wqh = up;  up += WSZ;
    u16* Wql = up;  up += WSZ;
    u16* Wkh = up;  up += WSZ;
    u16* Wkl = up;  up += WSZ;
    u16* Wvh = up;  up += WSZ;
    u16* Wvl = up;  up += WSZ;
    u16* Woh = up;  up += WSZ;
    u16* Wol = up;  up += WSZ;
    u16* Qb  = up;  up += 3 * QH;
    u16* Kb  = up;  up += 3 * QH;
    u16* gV  = up;  up += 2 * QH;
    u16* Kc  = up;  up += 3 * CK;
    u16* gVc = up;  up += 2 * CK;

    u16* Qb0 = Qb;           u16* Qb1 = Qb + QH;   u16* Qb2 = Qb + 2 * QH;
    u16* Kb0 = Kb;           u16* Kb1 = Kb + QH;   u16* Kb2 = Kb + 2 * QH;
    u16* gV0 = gV;           u16* gV1 = gV + QH;
    u16* Kc0 = Kc;           u16* Kc1 = Kc + CK;   u16* Kc2 = Kc + 2 * CK;
    u16* gVc0 = gVc;         u16* gVc1 = gVc + CK;

    // 0: hi/lo splits (x + all 4 weights)
    split_bf16_kernel<<<(int)(QH / 4 / 256), 256, 0, stream>>>(x, xh, xl, (int)(QH / 4));
    split_w4_kernel<<<dim3((int)(WSZ / 4 / 256), 4), 256, 0, stream>>>(
        Wq, Wk, Wv, Wo, Wqh, Wql, Wkh, Wkl, Wvh, Wvl, Woh, Wol);

    // 2: per-head centroid maps (independent of GEMM)
    cent_kernel<<<24, 256, 0, stream>>>(cent, Kc0, Kc1, Kc2, gVc0, gVc1, y2c, gm1c, rbcv, curv);

    // 1: QKV projections + fused hyperbolic maps (MFMA, dbuf, XCD-banded)
    gemm_qkv_mfma<<<1296, 256, 0, stream>>>(xh, xl, Wqh, Wql, Wkh, Wkl, Wvh, Wvl,
                                            bq, bk, bv,
                                            Qb0, Qb1, Qb2, Kb0, Kb1, Kb2, gV0, gV1,
                                            x2q, y2g, gm1, rbjv, curv);
    // 4: fused attention (MFMA, LDS-staged, XCD-affine, arcosh logit)
    attn_kernel<<<1728, 256, 0, stream>>>(Qb0, Qb1, Qb2, Kb0, Kb1, Kb2, Kc0, Kc1, Kc2,
                                          gV0, gV1, gVc0, gVc1,
                                          x2q, y2g, gm1, y2c, gm1c, rbjv, rbcv,
                                          sigr, curv, Oh, Ol);
    // 5: output projection (MFMA, dbuf, XCD-banded)
    gemm_o_mfma<<<432, 256, 0, stream>>>(Oh, Ol, Woh, Wol, bo, out);
}

// Round 15
// 370.872 us; speedup vs baseline: 1.1223x; 1.0037x over previous
//
#include <hip/hip_runtime.h>
#include <cstdint>
#include <cstddef>

#define B_  16
#define N_  576
#define D_  768
#define H_  12
#define HD_ 64
#define M_  128
#define J_  704   // N_ + M_

typedef unsigned short u16;
typedef __attribute__((ext_vector_type(8))) short bf16x8;
typedef __attribute__((ext_vector_type(4))) float f32x4;
typedef __attribute__((ext_vector_type(4))) unsigned short u16x4;
typedef __attribute__((ext_vector_type(8))) unsigned short u16x8;

// ---------------- helpers ----------------

__device__ __forceinline__ float softplus_f(float x) {
    return (x > 20.f) ? x : log1pf(expf(x));
}

__device__ __forceinline__ float wred_sum64(float v) {
#pragma unroll
    for (int m = 1; m < 64; m <<= 1) v += __shfl_xor(v, m, 64);
    return v;
}

__device__ __forceinline__ u16 bf16_rne(float f) {
    unsigned int u = __float_as_uint(f);
    unsigned int r = u + 0x7FFFu + ((u >> 16) & 1u);
    return (u16)(r >> 16);
}
__device__ __forceinline__ float bf16_tof(u16 h) {
    return __uint_as_float(((unsigned int)h) << 16);
}

// expmap0 total multiplier (division- and tanhf-free: v_rcp/v_exp).
__device__ __forceinline__ float expmap0_factor(float n2, float sc, float* n2out) {
    const float ATANH_1M1E5 = 6.1030335f;     // artanh(1 - 1e-5)
    const float LOG2E2 = 2.8853900817779268f; // 2*log2(e)
    float rsc = __builtin_amdgcn_rcpf(sc);
    float n0 = __builtin_amdgcn_sqrtf(fmaxf(n2, 1e-15f));
    float f1 = fminf(1.f, (ATANH_1M1E5 * rsc) * __builtin_amdgcn_rcpf(n0));  // pre-clip
    float n1 = n0 * f1;
    float a  = sc * n1;
    float e2a = __builtin_amdgcn_exp2f(a * LOG2E2);
    float th  = 1.f - 2.f * __builtin_amdgcn_rcpf(e2a + 1.f);   // tanh(a), a not tiny
    float yfac  = th * __builtin_amdgcn_rcpf(a);
    float f2 = fminf(1.f, 0.99999f * __builtin_amdgcn_rcpf(th)); // post-clip
    float fn = (th * rsc) * f2;
    *n2out = fn * fn;
    return f1 * yfac * f2;
}

__device__ __forceinline__ float artanh_fast(float z) {  // z in [0, 1-1e-7]
    return 0.5f * __logf((1.f + z) / (1.f - z));
}

// global -> LDS direct copy, 16B per lane (wave-uniform LDS base + lane*16)
typedef const __attribute__((address_space(1))) unsigned int* gas_u32;
typedef __attribute__((address_space(3))) unsigned int* las_u32;
__device__ __forceinline__ void gload_lds16(const u16* g, u16* l) {
    __builtin_amdgcn_global_load_lds((gas_u32)(const void*)g, (las_u32)(void*)l, 16, 0, 0);
}

// ---------------- kernel 0a: f32 -> bf16 hi/lo split (x) ----------------
__global__ __launch_bounds__(256) void split_bf16_kernel(
    const float* __restrict__ src, u16* __restrict__ hi, u16* __restrict__ lo, int n4)
{
    int i = blockIdx.x * 256 + threadIdx.x;
    if (i >= n4) return;
    float4 v = ((const float4*)src)[i];
    u16x4 h, l;
    h[0] = bf16_rne(v.x); l[0] = bf16_rne(v.x - bf16_tof(h[0]));
    h[1] = bf16_rne(v.y); l[1] = bf16_rne(v.y - bf16_tof(h[1]));
    h[2] = bf16_rne(v.z); l[2] = bf16_rne(v.z - bf16_tof(h[2]));
    h[3] = bf16_rne(v.w); l[3] = bf16_rne(v.w - bf16_tof(h[3]));
    ((u16x4*)hi)[i] = h;
    ((u16x4*)lo)[i] = l;
}

// ---------------- kernel 0b: split all 4 weight matrices in one launch ----------------
__global__ __launch_bounds__(256) void split_w4_kernel(
    const float* __restrict__ W0, const float* __restrict__ W1,
    const float* __restrict__ W2, const float* __restrict__ W3,
    u16* __restrict__ H0, u16* __restrict__ L0, u16* __restrict__ H1, u16* __restrict__ L1,
    u16* __restrict__ H2, u16* __restrict__ L2, u16* __restrict__ H3, u16* __restrict__ L3)
{
    int i = blockIdx.x * 256 + threadIdx.x;   // < WSZ/4 = 147456
    const int wsel = blockIdx.y;
    const float* src = wsel == 0 ? W0 : (wsel == 1 ? W1 : (wsel == 2 ? W2 : W3));
    u16* hi = wsel == 0 ? H0 : (wsel == 1 ? H1 : (wsel == 2 ? H2 : H3));
    u16* lo = wsel == 0 ? L0 : (wsel == 1 ? L1 : (wsel == 2 ? L2 : L3));
    float4 v = ((const float4*)src)[i];
    u16x4 h, l;
    h[0] = bf16_rne(v.x); l[0] = bf16_rne(v.x - bf16_tof(h[0]));
    h[1] = bf16_rne(v.y); l[1] = bf16_rne(v.y - bf16_tof(h[1]));
    h[2] = bf16_rne(v.z); l[2] = bf16_rne(v.z - bf16_tof(h[2]));
    h[3] = bf16_rne(v.w); l[3] = bf16_rne(v.w - bf16_tof(h[3]));
    ((u16x4*)hi)[i] = h;
    ((u16x4*)lo)[i] = l;
}

// ---------------- kernel 1: QKV projection + FUSED hyperbolic maps ----------------
// T4 schedule: dbuf LDS, counted vmcnt (never 0 in main loop), raw s_barriers.
//   STAGE(next->cur^1) ; vmcnt(8) [prev iter's loads landed] ; barrier ;
//   frag reads + MFMA(cur) ; barrier (read-release, no vm drain).
__global__ __launch_bounds__(256) void gemm_qkv_mfma(
    const u16* __restrict__ xh, const u16* __restrict__ xl,
    const u16* __restrict__ Wh0, const u16* __restrict__ Wl0,
    const u16* __restrict__ Wh1, const u16* __restrict__ Wl1,
    const u16* __restrict__ Wh2, const u16* __restrict__ Wl2,
    const float* __restrict__ bq, const float* __restrict__ bk, const float* __restrict__ bv,
    u16* __restrict__ Qb0, u16* __restrict__ Qb1, u16* __restrict__ Qb2,
    u16* __restrict__ Kb0, u16* __restrict__ Kb1, u16* __restrict__ Kb2,
    u16* __restrict__ gV0, u16* __restrict__ gV1,
    float* __restrict__ x2q, float* __restrict__ y2g, float* __restrict__ gm1,
    float* __restrict__ rbj,
    const float* __restrict__ curv_raw)
{
    __shared__ u16 Ah[2][4096], Al[2][4096], Bh[2][4096], Bl[2][4096];   // dbuf
    const int tid = threadIdx.x;
    const int w = tid >> 6, lane = tid & 63;
    const int wr = w >> 1, wc = w & 1;
    const int lrow = lane & 15, lk8 = (lane >> 4) << 3;
    const int lg = lane >> 4;
    // XCD-band swizzle: 1296 blocks = 8 XCDs x (9 mt x 18 yb)
    const int bid = blockIdx.x;
    const int xcd = bid & 7, ser = bid >> 3;       // ser < 162
    const int mt = xcd * 9 + (ser % 9);
    const int yb = ser / 9;                        // < 18
    const int which = yb / 6, ct = yb - which * 6;
    const u16* Bp_h = which == 0 ? Wh0 : (which == 1 ? Wh1 : Wh2);
    const u16* Bp_l = which == 0 ? Wl0 : (which == 1 ? Wl1 : Wl2);
    const int row0 = mt * 128, col0 = ct * 128;

    const size_t a0 = (size_t)(row0 + (2 * w + 0) * 16 + lrow) * 768 + lk8;
    const size_t a1 = a0 + 16 * 768;
    const size_t b0 = (size_t)(col0 + (2 * w + 0) * 16 + lrow) * 768 + lk8;
    const size_t b1 = b0 + 16 * 768;
    const int wo = (2 * w) * 512;

    auto STAGE = [&](int k0, int buf) {
        gload_lds16(xh + a0 + k0, &Ah[buf][wo]);
        gload_lds16(xh + a1 + k0, &Ah[buf][wo + 512]);
        gload_lds16(xl + a0 + k0, &Al[buf][wo]);
        gload_lds16(xl + a1 + k0, &Al[buf][wo + 512]);
        gload_lds16(Bp_h + b0 + k0, &Bh[buf][wo]);
        gload_lds16(Bp_h + b1 + k0, &Bh[buf][wo + 512]);
        gload_lds16(Bp_l + b0 + k0, &Bl[buf][wo]);
        gload_lds16(Bp_l + b1 + k0, &Bl[buf][wo + 512]);
    };

    f32x4 acc[4][4];
#pragma unroll
    for (int i = 0; i < 4; ++i)
#pragma unroll
        for (int j = 0; j < 4; ++j) acc[i][j] = (f32x4){0.f, 0.f, 0.f, 0.f};

    STAGE(0, 0);
    asm volatile("s_waitcnt vmcnt(0)" ::: "memory");
    __builtin_amdgcn_sched_barrier(0);
    __builtin_amdgcn_s_barrier();
    __builtin_amdgcn_sched_barrier(0);

    const int lo8 = lane * 8;
    int cur = 0;
    for (int k0 = 0; k0 < 768; k0 += 32) {
        if (k0 < 736) {
            STAGE(k0 + 32, cur ^ 1);                       // stays in flight across barrier
            asm volatile("s_waitcnt vmcnt(8)" ::: "memory"); // prev iter's 8 landed
        } else {
            asm volatile("s_waitcnt vmcnt(0)" ::: "memory");
        }
        __builtin_amdgcn_sched_barrier(0);
        __builtin_amdgcn_s_barrier();                      // cur fully populated block-wide
        __builtin_amdgcn_sched_barrier(0);
        bf16x8 aH[4], aL[4], bH[4], bL[4];
#pragma unroll
        for (int i = 0; i < 4; ++i) {
            aH[i] = *(const bf16x8*)(&Ah[cur][(wr * 4 + i) * 512 + lo8]);
            aL[i] = *(const bf16x8*)(&Al[cur][(wr * 4 + i) * 512 + lo8]);
            bH[i] = *(const bf16x8*)(&Bh[cur][(wc * 4 + i) * 512 + lo8]);
            bL[i] = *(const bf16x8*)(&Bl[cur][(wc * 4 + i) * 512 + lo8]);
        }
#pragma unroll
        for (int mi = 0; mi < 4; ++mi)
#pragma unroll
            for (int ni = 0; ni < 4; ++ni) {
                acc[mi][ni] = __builtin_amdgcn_mfma_f32_16x16x32_bf16(aH[mi], bH[ni], acc[mi][ni], 0, 0, 0);
                acc[mi][ni] = __builtin_amdgcn_mfma_f32_16x16x32_bf16(aH[mi], bL[ni], acc[mi][ni], 0, 0, 0);
                acc[mi][ni] = __builtin_amdgcn_mfma_f32_16x16x32_bf16(aL[mi], bH[ni], acc[mi][ni], 0, 0, 0);
            }
        __builtin_amdgcn_sched_barrier(0);
        __builtin_amdgcn_s_barrier();                      // read-release (no vm drain)
        __builtin_amdgcn_sched_barrier(0);
        cur ^= 1;
    }

    // ---------------- fused epilogue ----------------
    const float* bias = which == 0 ? bq : (which == 1 ? bk : bv);
    const int h = ct * 2 + wc;
    const int rbase = row0 + wr * 64 + (lg << 2);
    const float c  = softplus_f(curv_raw[0]);
    const float sc = sqrtf(c);
    float bvv[4];
#pragma unroll
    for (int ni = 0; ni < 4; ++ni) bvv[ni] = bias[h * 64 + ni * 16 + lrow];

#pragma unroll
    for (int mi = 0; mi < 4; ++mi) {
        float v4[4][4];   // [ni][r]
#pragma unroll
        for (int ni = 0; ni < 4; ++ni) {
            f32x4 a = acc[mi][ni];
#pragma unroll
            for (int r = 0; r < 4; ++r) v4[ni][r] = a[r] + bvv[ni];
        }
        // per-row sumsq: in-lane ni-sum first, then 4-step lrow butterfly
        float f_[4], n2o_[4];
#pragma unroll
        for (int r = 0; r < 4; ++r) {
            float s = v4[0][r] * v4[0][r];
#pragma unroll
            for (int ni = 1; ni < 4; ++ni) s = fmaf(v4[ni][r], v4[ni][r], s);
#pragma unroll
            for (int m = 1; m < 16; m <<= 1) s += __shfl_xor(s, m, 64);
            f_[r] = expmap0_factor(s, sc, &n2o_[r]);
        }
        const int row0g = rbase + mi * 16;          // 4 consecutive rows, same batch
        const int bb = row0g / 576;
        const int nn0 = row0g - bb * 576;
        const size_t gbase = ((size_t)(bb * 12 + h)) * 576 + nn0;
        if (which == 2) {
            float gmm[4];
#pragma unroll
            for (int r = 0; r < 4; ++r)
                gmm[r] = 2.f * __builtin_amdgcn_rcpf(fmaxf(1.f - c * n2o_[r], 1e-15f));
            if (lrow == 0) {
#pragma unroll
                for (int r = 0; r < 4; ++r) gm1[gbase + r] = gmm[r] - 1.f;
            }
#pragma unroll
            for (int ni = 0; ni < 4; ++ni) {
                const int hd = ni * 16 + lrow;
                u16x4 hs, ls;
#pragma unroll
                for (int r = 0; r < 4; ++r) {
                    float gv = v4[ni][r] * f_[r] * gmm[r];
                    u16 hb = bf16_rne(gv);
                    hs[r] = hb;
                    ls[r] = bf16_rne(gv - bf16_tof(hb));
                }
                const size_t dst = (((size_t)(bb * 12 + h)) * 64 + hd) * 576 + nn0;
                *(u16x4*)(gV0 + dst) = hs;
                *(u16x4*)(gV1 + dst) = ls;
            }
        } else {
            float* scal = which == 0 ? x2q : y2g;
            if (lrow == 0) {
#pragma unroll
                for (int r = 0; r < 4; ++r) scal[gbase + r] = n2o_[r];
                if (which == 1) {
#pragma unroll
                    for (int r = 0; r < 4; ++r)
                        rbj[gbase + r] = __builtin_amdgcn_rcpf(fmaf(-c, n2o_[r], 1.f));
                }
            }
            u16* P0 = which == 0 ? Qb0 : Kb0;
            u16* P1 = which == 0 ? Qb1 : Kb1;
            u16* P2 = which == 0 ? Qb2 : Kb2;
#pragma unroll
            for (int ni = 0; ni < 4; ++ni) {
                const int hd = ni * 16 + lrow;
#pragma unroll
                for (int r = 0; r < 4; ++r) {
                    float y = v4[ni][r] * f_[r];
                    u16 hb = bf16_rne(y);
                    float r1 = y - bf16_tof(hb);
                    u16 mb = bf16_rne(r1);
                    u16 lb2 = bf16_rne(r1 - bf16_tof(mb));
                    const size_t off = (gbase + r) * 64 + hd;
                    P0[off] = hb; P1[off] = mb; P2[off] = lb2;
                }
            }
        }
    }
}

// ---------------- kernel 5: output projection (T4 schedule) ----------------
__global__ __launch_bounds__(256) void gemm_o_mfma(
    const u16* __restrict__ Oh, const u16* __restrict__ Ol,
    const u16* __restrict__ Wh, const u16* __restrict__ Wl,
    const float* __restrict__ bo, float* __restrict__ out)
{
    __shared__ u16 Ah[2][4096], Al[2][4096], Bh[2][4096], Bl[2][4096];
    const int tid = threadIdx.x;
    const int w = tid >> 6, lane = tid & 63;
    const int wr = w >> 1, wc = w & 1;
    const int lrow = lane & 15, lk8 = (lane >> 4) << 3;
    // 432 blocks = 8 XCDs x (9 mt x 6 ct)
    const int bid = blockIdx.x;
    const int xcd = bid & 7, ser = bid >> 3;       // ser < 54
    const int mt = xcd * 9 + (ser % 9);
    const int ct = ser / 9;                        // < 6
    const int row0 = mt * 128, col0 = ct * 128;

    const size_t a0 = (size_t)(row0 + (2 * w + 0) * 16 + lrow) * 768 + lk8;
    const size_t a1 = a0 + 16 * 768;
    const size_t b0 = (size_t)(col0 + (2 * w + 0) * 16 + lrow) * 768 + lk8;
    const size_t b1 = b0 + 16 * 768;
    const int wo = (2 * w) * 512;

    auto STAGE = [&](int k0, int buf) {
        gload_lds16(Oh + a0 + k0, &Ah[buf][wo]);
        gload_lds16(Oh + a1 + k0, &Ah[buf][wo + 512]);
        gload_lds16(Ol + a0 + k0, &Al[buf][wo]);
        gload_lds16(Ol + a1 + k0, &Al[buf][wo + 512]);
        gload_lds16(Wh + b0 + k0, &Bh[buf][wo]);
        gload_lds16(Wh + b1 + k0, &Bh[buf][wo + 512]);
        gload_lds16(Wl + b0 + k0, &Bl[buf][wo]);
        gload_lds16(Wl + b1 + k0, &Bl[buf][wo + 512]);
    };

    f32x4 acc[4][4];
#pragma unroll
    for (int i = 0; i < 4; ++i)
#pragma unroll
        for (int j = 0; j < 4; ++j) acc[i][j] = (f32x4){0.f, 0.f, 0.f, 0.f};

    STAGE(0, 0);
    asm volatile("s_waitcnt vmcnt(0)" ::: "memory");
    __builtin_amdgcn_sched_barrier(0);
    __builtin_amdgcn_s_barrier();
    __builtin_amdgcn_sched_barrier(0);

    const int lo8 = lane * 8;
    int cur = 0;
    for (int k0 = 0; k0 < 768; k0 += 32) {
        if (k0 < 736) {
            STAGE(k0 + 32, cur ^ 1);
            asm volatile("s_waitcnt vmcnt(8)" ::: "memory");
        } else {
            asm volatile("s_waitcnt vmcnt(0)" ::: "memory");
        }
        __builtin_amdgcn_sched_barrier(0);
        __builtin_amdgcn_s_barrier();
        __builtin_amdgcn_sched_barrier(0);
        bf16x8 aH[4], aL[4], bH[4], bL[4];
#pragma unroll
        for (int i = 0; i < 4; ++i) {
            aH[i] = *(const bf16x8*)(&Ah[cur][(wr * 4 + i) * 512 + lo8]);
            aL[i] = *(const bf16x8*)(&Al[cur][(wr * 4 + i) * 512 + lo8]);
            bH[i] = *(const bf16x8*)(&Bh[cur][(wc * 4 + i) * 512 + lo8]);
            bL[i] = *(const bf16x8*)(&Bl[cur][(wc * 4 + i) * 512 + lo8]);
        }
#pragma unroll
        for (int mi = 0; mi < 4; ++mi)
#pragma unroll
            for (int ni = 0; ni < 4; ++ni) {
                acc[mi][ni] = __builtin_amdgcn_mfma_f32_16x16x32_bf16(aH[mi], bH[ni], acc[mi][ni], 0, 0, 0);
                acc[mi][ni] = __builtin_amdgcn_mfma_f32_16x16x32_bf16(aH[mi], bL[ni], acc[mi][ni], 0, 0, 0);
                acc[mi][ni] = __builtin_amdgcn_mfma_f32_16x16x32_bf16(aL[mi], bH[ni], acc[mi][ni], 0, 0, 0);
            }
        __builtin_amdgcn_sched_barrier(0);
        __builtin_amdgcn_s_barrier();
        __builtin_amdgcn_sched_barrier(0);
        cur ^= 1;
    }

    const int rbase = row0 + wr * 64 + ((lane >> 4) << 2);
#pragma unroll
    for (int ni = 0; ni < 4; ++ni) {
        const int colg = col0 + wc * 64 + ni * 16 + lrow;
        const float bv_ = bo[colg];
#pragma unroll
        for (int mi = 0; mi < 4; ++mi) {
            f32x4 a = acc[mi][ni];
#pragma unroll
            for (int r = 0; r < 4; ++r) {
                int row = rbase + mi * 16 + r;
                out[(size_t)row * 768 + colg] = a[r] + bv_;
            }
        }
    }
}

// ---------------- kernel 2: per-head centroid maps (once, shared across batch) ----------------
__global__ __launch_bounds__(256) void cent_kernel(
    const float* __restrict__ cent,
    u16* __restrict__ Kc0, u16* __restrict__ Kc1, u16* __restrict__ Kc2,
    u16* __restrict__ gVc0, u16* __restrict__ gVc1,
    float* __restrict__ y2c, float* __restrict__ gm1c, float* __restrict__ rbc,
    const float* __restrict__ curv_raw)
{
    __shared__ float gvt_s[64][65];
    const float c  = softplus_f(curv_raw[0]);
    const float sc = sqrtf(c);
    const int t = blockIdx.x;         // < 24
    const int h = t >> 1, ct = t & 1;
    const int w = threadIdx.x >> 6, lane = threadIdx.x & 63;
#pragma unroll 4
    for (int i = 0; i < 16; ++i) {
        const int m = ct * 64 + w * 16 + i;
        const size_t g = (size_t)h * 128 + m;
        float cv = cent[g * 64 + lane];
        float n2 = wred_sum64(cv * cv);
        float n2o;
        float f = expmap0_factor(n2, sc, &n2o);
        float ky = cv * f;
        u16 kh = bf16_rne(ky);
        float r1 = ky - bf16_tof(kh);
        u16 km = bf16_rne(r1);
        u16 kl = bf16_rne(r1 - bf16_tof(km));
        Kc0[g * 64 + lane] = kh; Kc1[g * 64 + lane] = km; Kc2[g * 64 + lane] = kl;
        float gmm = 2.f * __builtin_amdgcn_rcpf(fmaxf(1.f - c * n2o, 1e-15f));
        gvt_s[lane][w * 16 + i] = ky * gmm;
        if (lane == 0) {
            y2c[g] = n2o; gm1c[g] = gmm - 1.f;
            rbc[g] = __builtin_amdgcn_rcpf(fmaf(-c, n2o, 1.f));
        }
    }
    __syncthreads();
    const int hd = threadIdx.x >> 2, j0 = (threadIdx.x & 3) * 16;
    u16 hb[16], lb[16];
#pragma unroll
    for (int e = 0; e < 16; ++e) {
        float v = gvt_s[hd][j0 + e];
        hb[e] = bf16_rne(v);
        lb[e] = bf16_rne(v - bf16_tof(hb[e]));
    }
    const size_t dst = ((size_t)h * 64 + hd) * 128 + ct * 64 + j0;
    *(u16x8*)(gVc0 + dst)     = *(u16x8*)&hb[0];
    *(u16x8*)(gVc0 + dst + 8) = *(u16x8*)&hb[8];
    *(u16x8*)(gVc1 + dst)     = *(u16x8*)&lb[0];
    *(u16x8*)(gVc1 + dst + 8) = *(u16x8*)&lb[8];
}

// ---------------- kernel 4: fused hyperbolic attention (MFMA, LDS-staged K/V) ----------------
// Logit via the arcosh form of the Poincare distance (exactly 2*artanh(arg)):
// z = 1 + 2c*||x-y||^2 * ra * rb; W = exp2(c2h*lg^2), lg = log2(z + sqrt(z^2-1)).
__global__ __launch_bounds__(256) void attn_kernel(
    const u16* __restrict__ Qb0, const u16* __restrict__ Qb1, const u16* __restrict__ Qb2,
    const u16* __restrict__ Kb0, const u16* __restrict__ Kb1, const u16* __restrict__ Kb2,
    const u16* __restrict__ Kc0, const u16* __restrict__ Kc1, const u16* __restrict__ Kc2,
    const u16* __restrict__ gV0, const u16* __restrict__ gV1,
    const u16* __restrict__ gVc0, const u16* __restrict__ gVc1,
    const float* __restrict__ x2q, const float* __restrict__ y2g, const float* __restrict__ gm1,
    const float* __restrict__ y2c, const float* __restrict__ gm1c,
    const float* __restrict__ rbj, const float* __restrict__ rbc,
    const float* __restrict__ sigma_raw, const float* __restrict__ curv_raw,
    u16* __restrict__ Oh, u16* __restrict__ Ol)
{
    __shared__ __align__(16) u16 Kst[2][3][4096];  // [buf][plane][row*64 + swizzled col]
    __shared__ __align__(16) u16 Vst[2][4096];     // [plane][row*64 + swizzled col]
    __shared__ __align__(16) u16 wb_hi[4][1024];
    __shared__ __align__(16) u16 wb_lo[4][1024];

    const int blk = blockIdx.x;
    const int xcd = blk & 7;
    const int serial = blk >> 3;
    const int bhg = serial / 9;
    const int qt = serial - bhg * 9;
    const int bh = bhg * 8 + xcd;
    const int b = bh / 12, h = bh % 12;
    const float c  = softplus_f(curv_raw[0]);
    const float sc = sqrtf(c);
    const float sig = softplus_f(sigma_raw[h]) + 1e-6f;
    const float coef = -2.f / (c * sig * sig);   // logit = coef * artanh(arg)^2
    const float c2h  = coef * 0.25f * 0.6931471805599453f;  // exp2 basis

    const int tid = threadIdx.x;
    const int w = tid >> 6, lane = tid & 63;
    const int lr = lane & 15, lg = lane >> 4, lo8 = lg * 8;
    const int swl = (lr & 7) << 3;

    const size_t qbase = (size_t)bh * 576 + qt * 64;

    int srow[2], scol[2];
#pragma unroll
    for (int rr = 0; rr < 2; ++rr) {
        int cch = (rr * 4 + w) * 64 + lane;
        srow[rr] = cch >> 3;
        scol[rr] = ((cch & 7) ^ (srow[rr] & 7)) << 3;
    }
    const size_t kb_base = (size_t)bh * 576 * 64;
    const size_t kc_base = (size_t)h * 128 * 64;
    const size_t vb_base = (size_t)bh * 64 * 576;
    const size_t vc_base = (size_t)h * 64 * 128;

    auto stageK = [&](int t, int buf) {
        if (t < 9) {
            const size_t rb = kb_base + (size_t)t * 64 * 64;
#pragma unroll
            for (int rr = 0; rr < 2; ++rr) {
                const size_t so = rb + (size_t)srow[rr] * 64 + scol[rr];
                gload_lds16(Kb0 + so, &Kst[buf][0][(rr * 4 + w) * 512]);
                gload_lds16(Kb1 + so, &Kst[buf][1][(rr * 4 + w) * 512]);
                gload_lds16(Kb2 + so, &Kst[buf][2][(rr * 4 + w) * 512]);
            }
        } else {
            const size_t rb = kc_base + (size_t)(t - 9) * 64 * 64;
#pragma unroll
            for (int rr = 0; rr < 2; ++rr) {
                const size_t so = rb + (size_t)srow[rr] * 64 + scol[rr];
                gload_lds16(Kc0 + so, &Kst[buf][0][(rr * 4 + w) * 512]);
                gload_lds16(Kc1 + so, &Kst[buf][1][(rr * 4 + w) * 512]);
                gload_lds16(Kc2 + so, &Kst[buf][2][(rr * 4 + w) * 512]);
            }
        }
    };
    auto stageV = [&](int t) {
        if (t < 9) {
            const size_t rb = vb_base + (size_t)t * 64;
#pragma unroll
            for (int rr = 0; rr < 2; ++rr) {
                const size_t so = rb + (size_t)srow[rr] * 576 + scol[rr];
                gload_lds16(gV0 + so, &Vst[0][(rr * 4 + w) * 512]);
                gload_lds16(gV1 + so, &Vst[1][(rr * 4 + w) * 512]);
            }
        } else {
            const size_t rb = vc_base + (size_t)(t - 9) * 64;
#pragma unroll
            for (int rr = 0; rr < 2; ++rr) {
                const size_t so = rb + (size_t)srow[rr] * 128 + scol[rr];
                gload_lds16(gVc0 + so, &Vst[0][(rr * 4 + w) * 512]);
                gload_lds16(gVc1 + so, &Vst[1][(rr * 4 + w) * 512]);
            }
        }
    };

    bf16x8 aQh[2], aQm[2], aQl[2];
    {
        const size_t qrow = (qbase + w * 16 + lr) * 64;
#pragma unroll
        for (int kt = 0; kt < 2; ++kt) {
            const size_t o = qrow + kt * 32 + lo8;
            aQh[kt] = *(const bf16x8*)(Qb0 + o);
            aQm[kt] = *(const bf16x8*)(Qb1 + o);
            aQl[kt] = *(const bf16x8*)(Qb2 + o);
        }
    }
    float x2r[4], Pr[4];
#pragma unroll
    for (int r = 0; r < 4; ++r) {
        float x2 = x2q[qbase + w * 16 + lg * 4 + r];
        x2r[r] = x2;
        Pr[r] = (c + c) / fmaf(-c, x2, 1.f);    // 2c * ra, ra = 1/(1-c*x2)
    }

    f32x4 pv[4];
#pragma unroll
    for (int i = 0; i < 4; ++i) pv[i] = (f32x4){0.f, 0.f, 0.f, 0.f};
    float den[4] = {0.f, 0.f, 0.f, 0.f};

    u16* wbh = &wb_hi[w][0];
    u16* wbl = &wb_lo[w][0];

    stageK(0, 0);
    __syncthreads();

    int cur = 0;
    for (int jt = 0; jt < 11; ++jt) {
        const int jb = jt * 64;

        if (jt < 10) stageK(jt + 1, cur ^ 1);
        stageV(jt);

        const float* y2p;
        const float* gm1p;
        const float* rbp;
        if (jt < 9) {
            y2p = y2g + (size_t)bh * 576 + jb;  gm1p = gm1 + (size_t)bh * 576 + jb;
            rbp = rbj + (size_t)bh * 576 + jb;
        } else {
            y2p = y2c + (size_t)h * 128 + (jb - 576); gm1p = gm1c + (size_t)h * 128 + (jb - 576);
            rbp = rbc + (size_t)h * 128 + (jb - 576);
        }

        const u16* kp0 = &Kst[cur][0][0];
        const u16* kp1 = &Kst[cur][1][0];
        const u16* kp2 = &Kst[cur][2][0];
        f32x4 sf[4];
        float y2v[4], gm1v[4], rbv[4];
#pragma unroll
        for (int jf = 0; jf < 4; ++jf) {
            y2v[jf] = y2p[jf * 16 + lr];
            gm1v[jf] = gm1p[jf * 16 + lr];
            rbv[jf] = rbp[jf * 16 + lr];
            const int rb = (jf * 16 + lr) * 64;
            f32x4 s = (f32x4){0.f, 0.f, 0.f, 0.f};
#pragma unroll
            for (int kt = 0; kt < 2; ++kt) {
                const int o = rb + ((kt * 32 + lo8) ^ swl);
                bf16x8 kh = *(const bf16x8*)(kp0 + o);
                bf16x8 km = *(const bf16x8*)(kp1 + o);
                bf16x8 kl = *(const bf16x8*)(kp2 + o);
                s = __builtin_amdgcn_mfma_f32_16x16x32_bf16(aQh[kt], kh, s, 0, 0, 0);
                s = __builtin_amdgcn_mfma_f32_16x16x32_bf16(aQh[kt], km, s, 0, 0, 0);
                s = __builtin_amdgcn_mfma_f32_16x16x32_bf16(aQm[kt], kh, s, 0, 0, 0);
                s = __builtin_amdgcn_mfma_f32_16x16x32_bf16(aQm[kt], km, s, 0, 0, 0);
                s = __builtin_amdgcn_mfma_f32_16x16x32_bf16(aQh[kt], kl, s, 0, 0, 0);
                s = __builtin_amdgcn_mfma_f32_16x16x32_bf16(aQl[kt], kh, s, 0, 0, 0);
            }
            sf[jf] = s;
        }

        // ---- xy -> W via arcosh form (division-free, 3 transcendentals)
#pragma unroll
        for (int jf = 0; jf < 4; ++jf) {
            const float y2 = y2v[jf];
            const float rb_ = rbv[jf];
#pragma unroll
            for (int r = 0; r < 4; ++r) {
                float xy = sf[jf][r];
                float sxy = x2r[r] + y2;
                float u = fmaf(-2.f, xy, sxy);           // ||x-y||^2
                float krr = Pr[r] * rb_;                 // 2c*ra*rb
                float z = fmaxf(fmaf(krr, u, 1.f), 1.f);
                float zm = fmaxf(fmaf(z, z, -1.f), 0.f);
                float lg2 = __builtin_amdgcn_logf(z + __builtin_amdgcn_sqrtf(zm));
                float wv_ = __builtin_amdgcn_exp2f(c2h * (lg2 * lg2));
                sf[jf][r] = wv_;
                den[r] = fmaf(wv_, gm1v[jf], den[r]);
            }
        }

#pragma unroll
        for (int r = 0; r < 4; ++r) {
            const int row = lg * 4 + r;
            const int sw = (row & 7) << 3;
#pragma unroll
            for (int jf = 0; jf < 4; ++jf) {
                const int colu = (jf * 16 + lr) ^ sw;
                float wv_ = sf[jf][r];
                u16 hb = bf16_rne(wv_);
                wbh[row * 64 + colu] = hb;
                wbl[row * 64 + colu] = bf16_rne(wv_ - bf16_tof(hb));
            }
        }

        __syncthreads();   // V staged (vmcnt drained); K prefetch also landed

        bf16x8 aWh[2], aWl[2];
#pragma unroll
        for (int kt = 0; kt < 2; ++kt) {
            const int colu = (kt * 32 + lo8) ^ swl;
            aWh[kt] = *(const bf16x8*)(wbh + lr * 64 + colu);
            aWl[kt] = *(const bf16x8*)(wbl + lr * 64 + colu);
        }

#pragma unroll
        for (int hf = 0; hf < 4; ++hf) {
            const int rb = (hf * 16 + lr) * 64;
#pragma unroll
            for (int kt = 0; kt < 2; ++kt) {
                const int o = rb + ((kt * 32 + lo8) ^ swl);
                bf16x8 vh = *(const bf16x8*)(&Vst[0][o]);
                bf16x8 vl = *(const bf16x8*)(&Vst[1][o]);
                pv[hf] = __builtin_amdgcn_mfma_f32_16x16x32_bf16(aWh[kt], vh, pv[hf], 0, 0, 0);
                pv[hf] = __builtin_amdgcn_mfma_f32_16x16x32_bf16(aWh[kt], vl, pv[hf], 0, 0, 0);
                pv[hf] = __builtin_amdgcn_mfma_f32_16x16x32_bf16(aWl[kt], vh, pv[hf], 0, 0, 0);
            }
        }

        __syncthreads();
        cur ^= 1;
    }

#pragma unroll
    for (int r = 0; r < 4; ++r) {
        float d = den[r];
#pragma unroll
        for (int msk = 1; msk < 16; msk <<= 1) d += __shfl_xor(d, msk, 64);
        float rd = 1.f / d;                      // den > 0 always (gamma-1 >= 1)
        float o_[4];
        float n2 = 0.f;
#pragma unroll
        for (int hf = 0; hf < 4; ++hf) { o_[hf] = pv[hf][r] * rd; n2 = fmaf(o_[hf], o_[hf], n2); }
#pragma unroll
        for (int msk = 1; msk < 16; msk <<= 1) n2 += __shfl_xor(n2, msk, 64);
        float nrm = sqrtf(fmaxf(n2, 1e-15f));
        float arg = fminf(sc * nrm, 1.f - 1e-7f);
        float t = artanh_fast(arg);
        float f = 0.5f * t / (sc * nrm);
        const int nrow = qt * 64 + w * 16 + lg * 4 + r;
        const size_t dst = ((size_t)(b * 576 + nrow)) * 768 + h * 64;
#pragma unroll
        for (int hf = 0; hf < 4; ++hf) {
            float val = o_[hf] * f;
            u16 hb = bf16_rne(val);
            Oh[dst + hf * 16 + lr] = hb;
            Ol[dst + hf * 16 + lr] = bf16_rne(val - bf16_tof(hb));
        }
    }
}

// ---------------- launcher ----------------
extern "C" void kernel_launch(void* const* d_in, const int* in_sizes, int n_in,
                              void* d_out, int out_size, void* d_ws, size_t ws_size,
                              hipStream_t stream) {
    (void)in_sizes; (void)n_in; (void)out_size; (void)ws_size;
    const float* x    = (const float*)d_in[0];
    const float* Wq   = (const float*)d_in[1];
    const float* bq   = (const float*)d_in[2];
    const float* Wk   = (const float*)d_in[3];
    const float* bk   = (const float*)d_in[4];
    const float* Wv   = (const float*)d_in[5];
    const float* bv   = (const float*)d_in[6];
    const float* Wo   = (const float*)d_in[7];
    const float* bo   = (const float*)d_in[8];
    const float* cent = (const float*)d_in[9];
    const float* curv = (const float*)d_in[10];
    const float* sigr = (const float*)d_in[11];
    float* out = (float*)d_out;

    const size_t QH  = (size_t)B_ * H_ * N_ * 64;   // 7,077,888 (also K/V token size)
    const size_t CK  = (size_t)H_ * M_ * 64;        // 98,304 centroid-plane size
    const size_t WSZ = (size_t)D_ * D_;             // 589,824

    float* fp = (float*)d_ws;
    float* x2q  = fp;            fp += (size_t)B_ * H_ * N_;
    float* y2g  = fp;            fp += (size_t)B_ * H_ * N_;
    float* gm1  = fp;            fp += (size_t)B_ * H_ * N_;
    float* rbjv = fp;            fp += (size_t)B_ * H_ * N_;
    float* y2c  = fp;            fp += (size_t)H_ * M_;
    float* gm1c = fp;            fp += (size_t)H_ * M_;
    float* rbcv = fp;            fp += (size_t)H_ * M_;
    u16* up = (u16*)fp;
    u16* xh  = up;  up += QH;     // aliased with Oh (xh dead before attn writes Oh)
    u16* xl  = up;  up += QH;     // aliased with Ol
    u16* Oh  = xh;
    u16* Ol  = xl;
    u16* Wqh = up;  up += WSZ;
    u16* Wql = up;  up += WSZ;
    u16* Wkh = up;  up += WSZ;
    u16* Wkl = up;  up += WSZ;
    u16* Wvh = up;  up += WSZ;
    u16* Wvl = up;  up += WSZ;
    u16* Woh = up;  up += WSZ;
    u16* Wol = up;  up += WSZ;
    u16* Qb  = up;  up += 3 * QH;
    u16* Kb  = up;  up += 3 * QH;
    u16* gV  = up;  up += 2 * QH;
    u16* Kc  = up;  up += 3 * CK;
    u16* gVc = up;  up += 2 * CK;

    u16* Qb0 = Qb;           u16* Qb1 = Qb + QH;   u16* Qb2 = Qb + 2 * QH;
    u16* Kb0 = Kb;           u16* Kb1 = Kb + QH;   u16* Kb2 = Kb + 2 * QH;
    u16* gV0 = gV;           u16* gV1 = gV + QH;
    u16* Kc0 = Kc;           u16* Kc1 = Kc + CK;   u16* Kc2 = Kc + 2 * CK;
    u16* gVc0 = gVc;         u16* gVc1 = gVc + CK;

    // 0: hi/lo splits (x + all 4 weights)
    split_bf16_kernel<<<(int)(QH / 4 / 256), 256, 0, stream>>>(x, xh, xl, (int)(QH / 4));
    split_w4_kernel<<<dim3((int)(WSZ / 4 / 256), 4), 256, 0, stream>>>(
        Wq, Wk, Wv, Wo, Wqh, Wql, Wkh, Wkl, Wvh, Wvl, Woh, Wol);

    // 2: per-head centroid maps (independent of GEMM)
    cent_kernel<<<24, 256, 0, stream>>>(cent, Kc0, Kc1, Kc2, gVc0, gVc1, y2c, gm1c, rbcv, curv);

    // 1: QKV projections + fused hyperbolic maps (MFMA, T4 counted-vmcnt, XCD-banded)
    gemm_qkv_mfma<<<1296, 256, 0, stream>>>(xh, xl, Wqh, Wql, Wkh, Wkl, Wvh, Wvl,
                                            bq, bk, bv,
                                            Qb0, Qb1, Qb2, Kb0, Kb1, Kb2, gV0, gV1,
                                            x2q, y2g, gm1, rbjv, curv);
    // 4: fused attention (MFMA, LDS-staged, XCD-affine, arcosh logit)
    attn_kernel<<<1728, 256, 0, stream>>>(Qb0, Qb1, Qb2, Kb0, Kb1, Kb2, Kc0, Kc1, Kc2,
                                          gV0, gV1, gVc0, gVc1,
                                          x2q, y2g, gm1, y2c, gm1c, rbjv, rbcv,
                                          sigr, curv, Oh, Ol);
    // 5: output projection (MFMA, T4 counted-vmcnt, XCD-banded)
    gemm_o_mfma<<<432, 256, 0, stream>>>(Oh, Ol, Woh, Wol, bo, out);
}